// Round 8
// baseline (289.310 us; speedup 1.0000x reference)
//
#include <hip/hip_runtime.h>

typedef unsigned short u16;
typedef unsigned int u32;
using bfrag = __attribute__((ext_vector_type(8))) short;
using f4v   = __attribute__((ext_vector_type(4))) float;

#define DIV_UP(a,b) (((a)+(b)-1)/(b))
#define PTILE 4096
#define CHB 512
#define CHSH 9
#define NBKT 256
#define MFMA(a,b,c) __builtin_amdgcn_mfma_f32_16x16x32_bf16(a,b,c,0,0,0)

__device__ inline u16 f2bf(float f){
  union { float f; u32 u; } v; v.f = f;
  u32 u = v.u;
  return (u16)((u + 0x7fffu + ((u >> 16) & 1u)) >> 16);
}
__device__ inline float bf2f(u16 h){
  union { u32 u; float f; } v; v.u = ((u32)h) << 16;
  return v.f;
}
__device__ inline bfrag ldA(const u16* A, long r, int koff, int lane){
  return *reinterpret_cast<const bfrag*>(A + r*64 + koff + ((lane>>4)<<3));
}
__device__ inline bfrag ldW(const u16* Wf, int kb, int cb, int lane){
  return *reinterpret_cast<const bfrag*>(Wf + (((kb*4+cb)*64 + lane)<<3));
}

// --- per-wave 16x64 C-tile -> A-fragment transpose via swizzled LDS (no barrier) ---
__device__ inline void xpose_store(u16* sT, int lane, const f4v (&acc)[4]){
  const int cl = lane & 15, g = lane >> 4;
#pragma unroll
  for (int j = 0; j < 4; ++j){
    const int lr = g*4 + j;
#pragma unroll
    for (int cb = 0; cb < 4; ++cb){
      const int colblk = cb*2 + (cl >> 3);
      const int gr = colblk ^ (lr & 7);
      sT[lr*64 + gr*8 + (cl & 7)] = f2bf(acc[cb][j]);
    }
  }
}
__device__ inline bfrag xpose_load(const u16* sT, int lane, int kb){
  const int row = lane & 15, colblk = kb*4 + (lane >> 4);
  const int gr = colblk ^ (row & 7);
  return *reinterpret_cast<const bfrag*>(sT + row*64 + gr*8);
}

// ---------------- edge radix-partition into 256 target-chunk buckets ----------------
__global__ void initBkt_k(int* __restrict__ bktCnt, int bstride){
  if (threadIdx.x < NBKT) bktCnt[threadIdx.x] = threadIdx.x * bstride;
}
__global__ void partition_k(const int* __restrict__ tgt, const int* __restrict__ src,
                            int E, int* __restrict__ bktCnt, int2* __restrict__ bkt){
  __shared__ int hist[NBKT], base[NBKT], pos[NBKT];
  const int t = threadIdx.x;
  hist[t] = 0;
  __syncthreads();
  const int e0 = blockIdx.x * PTILE;
  const int e1 = (e0 + PTILE < E) ? e0 + PTILE : E;
  for (int i = e0 + t; i < e1; i += NBKT)
    atomicAdd(&hist[tgt[i] >> CHSH], 1);
  __syncthreads();
  base[t] = (hist[t] > 0) ? atomicAdd(&bktCnt[t], hist[t]) : 0;
  pos[t] = 0;
  __syncthreads();
  for (int i = e0 + t; i < e1; i += NBKT){
    int tv = tgt[i], sv = src[i];
    int c = tv >> CHSH;
    int p = base[c] + atomicAdd(&pos[c], 1);
    bkt[p] = make_int2(tv, sv);
  }
}

// ---------------- per-chunk LDS counting sort: one workgroup per chunk ----------------
__global__ __launch_bounds__(CHB) void sortChunk_k(const int2* __restrict__ bkt,
    const int* __restrict__ bktCnt, int bstride, int N,
    int* __restrict__ cnt, int* __restrict__ off, int* __restrict__ perm){
  __shared__ int hist[CHB], sbase[CHB];
  const int c = blockIdx.x, t = threadIdx.x;
  const int lo = c * CHB;
  const int s = c * bstride, e = bktCnt[c];
  hist[t] = 0;
  __syncthreads();
  for (int i = s + t; i < e; i += CHB)
    atomicAdd(&hist[bkt[i].x - lo], 1);
  __syncthreads();
  const int v = hist[t];
  for (int o = 1; o < CHB; o <<= 1){
    int add = (t >= o) ? hist[t - o] : 0;
    __syncthreads();
    hist[t] += add;
    __syncthreads();
  }
  const int excl = hist[t] - v;
  if (lo + t < N){ cnt[lo + t] = v; off[lo + t] = s + excl; }
  sbase[t] = s + excl;
  __syncthreads();
  hist[t] = 0;
  __syncthreads();
  for (int i = s + t; i < e; i += CHB){
    int2 ed = bkt[i];
    int r = ed.x - lo;
    int p = sbase[r] + atomicAdd(&hist[r], 1);
    perm[p] = ed.y;
  }
}

// ---------------- weight prep: one block per output row (195x64) ----------------
__global__ void matW_k(const float* __restrict__ W_self, const float* __restrict__ W_comb,
                       const float* __restrict__ b_self,
                       float* __restrict__ WsWct, float* __restrict__ bsWct){
  const int b = blockIdx.x;            // 3 layers * 65 rows
  const int i = b / 65, r = b % 65;
  const int c = threadIdx.x;           // 64
  const float* Wc = W_comb + i*8192;   // rows 0..63 (top half)
  float s = 0.f;
  if (r < 64){
    const float* a = W_self + i*4096 + r*64;
#pragma unroll 8
    for (int k = 0; k < 64; ++k) s += a[k] * Wc[k*64 + c];
    WsWct[i*4096 + r*64 + c] = s;
  } else {
    const float* a = b_self + i*64;
#pragma unroll 8
    for (int k = 0; k < 64; ++k) s += a[k] * Wc[k*64 + c];
    bsWct[i*64 + c] = s;
  }
}

// ---------------- all effective-weight builds in one grid-strided kernel ----------------
// Wle is 320x64: rows 0..255 = zg2*W_lagg (+ zg0*I at 192..255), rows 256..319 = zg1*I
__global__ void buildAll_k(const float* __restrict__ W_self, const float* __restrict__ W_comb,
    const float* __restrict__ b_self, const float* __restrict__ b_comb,
    const float* __restrict__ Z_comb, const float* __restrict__ WsWct,
    const float* __restrict__ bsWct,
    const float* __restrict__ W_lc, const float* __restrict__ b_lc,
    const float* __restrict__ Z_lc,
    const float* __restrict__ W_lagg, const float* __restrict__ b_lagg,
    const float* __restrict__ Z_lagg,
    float* __restrict__ W1eff, float* __restrict__ W2eff, float* __restrict__ beff,
    float* __restrict__ Wlceff, float* __restrict__ blceff,
    float* __restrict__ Wle, float* __restrict__ ble){
  int idx = blockIdx.x*blockDim.x + threadIdx.x;
  if (idx < 12288){
    int i = idx >> 12, rem = idx & 4095, k = rem >> 6, c = rem & 63;
    float zc0 = Z_comb[i*2], zc1 = Z_comb[i*2+1];
    W1eff[idx] = zc0*W_self[idx] + zc1*WsWct[idx];
    W2eff[idx] = (k == c ? zc0 : 0.f) + zc1*W_comb[i*8192 + (64 + k)*64 + c];
    return;
  }
  idx -= 12288;
  if (idx < 16384){
    int i = idx >> 13, rem = idx & 8191, k = rem >> 6, c = rem & 63;
    float z0 = Z_lc[i*3], z1 = Z_lc[i*3+1], z2 = Z_lc[i*3+2];
    float idv = (k < 64) ? (k == c ? z1 : 0.f) : ((k - 64) == c ? (z0 + z1) : 0.f);
    Wlceff[idx] = z2*W_lc[idx] + idv;
    return;
  }
  idx -= 16384;
  if (idx < 20480){
    int k = idx >> 6, c = idx & 63;
    float v = (k < 256) ? Z_lagg[2]*W_lagg[idx] : 0.f;
    if (k >= 192 && k < 256 && (k - 192) == c) v += Z_lagg[0];
    if (k >= 256 && (k - 256) == c) v += Z_lagg[1];
    Wle[idx] = v;
    return;
  }
  idx -= 20480;
  if (idx < 192){
    int i = idx >> 6;
    float zc0 = Z_comb[i*2], zc1 = Z_comb[i*2+1];
    beff[idx] = zc0*b_self[idx] + zc1*(bsWct[idx] + b_comb[idx]);
    return;
  }
  idx -= 192;
  if (idx < 128){
    int i = idx >> 6;
    blceff[idx] = Z_lc[i*3+2]*b_lc[idx];
    return;
  }
  idx -= 128;
  if (idx < 64) ble[idx] = Z_lagg[2]*b_lagg[idx];
}

// ---------------- pack fp32 [K][64] -> bf16 MFMA B-fragment layout ----------------
struct PackJobs {
  const float* src[15];
  u16* dst[15];
  int nkb[15];
};
__global__ void pack_all_k(PackJobs pj){
  const int job = blockIdx.x >> 4, kb = blockIdx.x & 15;
  if (kb >= pj.nkb[job]) return;
  const int t = threadIdx.x, cb = t >> 6, lane = t & 63;
  const float* S = pj.src[job];
  u16* D = pj.dst[job] + (((kb*4 + cb)*64 + lane) << 3);
  const int kbase = kb*32 + ((lane >> 4) << 3), c = cb*16 + (lane & 15);
#pragma unroll
  for (int j = 0; j < 8; ++j) D[j] = f2bf(S[(kbase + j)*64 + c]);
}

// ---------------- GEMM pre: fp32 A [N][128] -> emb0, fused xnl0 = emb0@Wnbr0 + bnbr0 ----------------
__global__ __launch_bounds__(256) void gemmP_k(const float* __restrict__ X,
    const u16* __restrict__ Wf, const float* __restrict__ bias,
    const u16* __restrict__ Wn, const float* __restrict__ bn,
    u16* __restrict__ out, u16* __restrict__ xnl, int N){
  __shared__ u16 sT[4][1024];
  const int lane = threadIdx.x & 63, w = threadIdx.x >> 6;
  const int R = blockIdx.x*64 + w*16;
  bfrag wf[4][4], wn[2][4];
#pragma unroll
  for (int kb = 0; kb < 4; ++kb)
#pragma unroll
    for (int cb = 0; cb < 4; ++cb) wf[kb][cb] = ldW(Wf, kb, cb, lane);
#pragma unroll
  for (int kb = 0; kb < 2; ++kb)
#pragma unroll
    for (int cb = 0; cb < 4; ++cb) wn[kb][cb] = ldW(Wn, kb, cb, lane);
  float bv[4], bnv[4];
#pragma unroll
  for (int cb = 0; cb < 4; ++cb){ bv[cb] = bias[cb*16 + (lane & 15)]; bnv[cb] = bn[cb*16 + (lane & 15)]; }
  const long ra = (R + (lane & 15) < N) ? (R + (lane & 15)) : (N - 1);
  f4v acc[4] = {f4v{0,0,0,0}, f4v{0,0,0,0}, f4v{0,0,0,0}, f4v{0,0,0,0}};
#pragma unroll
  for (int kb = 0; kb < 4; ++kb){
    const float* ap = X + ra*128 + kb*32 + ((lane >> 4) << 3);
    float4 q0 = *reinterpret_cast<const float4*>(ap);
    float4 q1 = *reinterpret_cast<const float4*>(ap + 4);
    bfrag a;
    a[0] = (short)f2bf(q0.x); a[1] = (short)f2bf(q0.y);
    a[2] = (short)f2bf(q0.z); a[3] = (short)f2bf(q0.w);
    a[4] = (short)f2bf(q1.x); a[5] = (short)f2bf(q1.y);
    a[6] = (short)f2bf(q1.z); a[7] = (short)f2bf(q1.w);
#pragma unroll
    for (int cb = 0; cb < 4; ++cb) acc[cb] = MFMA(a, wf[kb][cb], acc[cb]);
  }
#pragma unroll
  for (int cb = 0; cb < 4; ++cb)
#pragma unroll
    for (int j = 0; j < 4; ++j) acc[cb][j] += bv[cb];
  const int rbase = R + ((lane >> 4) << 2), cl = lane & 15;
#pragma unroll
  for (int cb = 0; cb < 4; ++cb)
#pragma unroll
    for (int j = 0; j < 4; ++j){
      int r = rbase + j;
      if (r < N) out[(size_t)r*64 + cb*16 + cl] = f2bf(acc[cb][j]);
    }
  // fused x_nl0
  xpose_store(sT[w], lane, acc);
  f4v ac2[4] = {f4v{0,0,0,0}, f4v{0,0,0,0}, f4v{0,0,0,0}, f4v{0,0,0,0}};
#pragma unroll
  for (int kb = 0; kb < 2; ++kb){
    bfrag a = xpose_load(sT[w], lane, kb);
#pragma unroll
    for (int cb = 0; cb < 4; ++cb) ac2[cb] = MFMA(a, wn[kb][cb], ac2[cb]);
  }
#pragma unroll
  for (int cb = 0; cb < 4; ++cb)
#pragma unroll
    for (int j = 0; j < 4; ++j){
      int r = rbase + j;
      if (r < N) xnl[(size_t)r*64 + cb*16 + cl] = f2bf(ac2[cb][j] + bnv[cb]);
    }
}

// ---------------- GEMM combine: h = x@W1eff + xn@W2eff + beff; act mix; layernorm ----------------
__global__ __launch_bounds__(256) void gemmC_k(const u16* __restrict__ A1,
    const u16* __restrict__ A2, const u16* __restrict__ Wf1, const u16* __restrict__ Wf2,
    const float* __restrict__ beff, const float* __restrict__ lng, const float* __restrict__ lnb,
    const float* __restrict__ Zact, const float* __restrict__ prelu,
    u16* __restrict__ out, int N){
  const int lane = threadIdx.x & 63, w = threadIdx.x >> 6;
  const int R = blockIdx.x*64 + w*16;
  bfrag wf1[2][4], wf2[2][4];
#pragma unroll
  for (int kb = 0; kb < 2; ++kb)
#pragma unroll
    for (int cb = 0; cb < 4; ++cb){ wf1[kb][cb] = ldW(Wf1, kb, cb, lane); wf2[kb][cb] = ldW(Wf2, kb, cb, lane); }
  float bv[4], lgv[4], lbv[4];
#pragma unroll
  for (int cb = 0; cb < 4; ++cb){
    int c = cb*16 + (lane & 15);
    bv[cb] = beff[c]; lgv[cb] = lng[c]; lbv[cb] = lnb[c];
  }
  const float zt0 = Zact[0], zt1 = Zact[1], pw = prelu[0];
  const long ra = (R + (lane & 15) < N) ? (R + (lane & 15)) : (N - 1);
  f4v acc[4] = {f4v{0,0,0,0}, f4v{0,0,0,0}, f4v{0,0,0,0}, f4v{0,0,0,0}};
#pragma unroll
  for (int kb = 0; kb < 2; ++kb){
    bfrag a = ldA(A1, ra, kb*32, lane);
#pragma unroll
    for (int cb = 0; cb < 4; ++cb) acc[cb] = MFMA(a, wf1[kb][cb], acc[cb]);
  }
#pragma unroll
  for (int kb = 0; kb < 2; ++kb){
    bfrag a = ldA(A2, ra, kb*32, lane);
#pragma unroll
    for (int cb = 0; cb < 4; ++cb) acc[cb] = MFMA(a, wf2[kb][cb], acc[cb]);
  }
#pragma unroll
  for (int cb = 0; cb < 4; ++cb)
#pragma unroll
    for (int j = 0; j < 4; ++j){
      float v = acc[cb][j] + bv[cb];
      v = zt0*fmaxf(v, 0.f) + zt1*((v > 0.f) ? v : pw*v);
      acc[cb][j] = v;
    }
  const int rbase = R + ((lane >> 4) << 2), cl = lane & 15;
#pragma unroll
  for (int j = 0; j < 4; ++j){
    float s = acc[0][j] + acc[1][j] + acc[2][j] + acc[3][j];
    s += __shfl_xor(s, 1, 64); s += __shfl_xor(s, 2, 64);
    s += __shfl_xor(s, 4, 64); s += __shfl_xor(s, 8, 64);
    float mu = s * 0.015625f;
    float d0 = acc[0][j]-mu, d1 = acc[1][j]-mu, d2 = acc[2][j]-mu, d3 = acc[3][j]-mu;
    float q = d0*d0 + d1*d1 + d2*d2 + d3*d3;
    q += __shfl_xor(q, 1, 64); q += __shfl_xor(q, 2, 64);
    q += __shfl_xor(q, 4, 64); q += __shfl_xor(q, 8, 64);
    float sd = rsqrtf(q * 0.015625f + 1e-5f);
    int r = rbase + j;
    if (r < N){
      out[(size_t)r*64 +  0 + cl] = f2bf(d0*sd*lgv[0] + lbv[0]);
      out[(size_t)r*64 + 16 + cl] = f2bf(d1*sd*lgv[1] + lbv[1]);
      out[(size_t)r*64 + 32 + cl] = f2bf(d2*sd*lgv[2] + lbv[2]);
      out[(size_t)r*64 + 48 + cl] = f2bf(d3*sd*lgv[3] + lbv[3]);
    }
  }
}

// ---------------- layer-connect (K=128 concat) fused with next layer's x_nl ----------------
__global__ __launch_bounds__(256) void lc_k(const u16* __restrict__ A1,
    const u16* __restrict__ A2, const u16* __restrict__ Wf,
    const float* __restrict__ bias, const u16* __restrict__ Wn,
    const float* __restrict__ bn, u16* __restrict__ out, u16* __restrict__ xnl, int N){
  __shared__ u16 sT[4][1024];
  const int lane = threadIdx.x & 63, w = threadIdx.x >> 6;
  const int R = blockIdx.x*64 + w*16;
  bfrag wf[4][4], wn[2][4];
#pragma unroll
  for (int kb = 0; kb < 4; ++kb)
#pragma unroll
    for (int cb = 0; cb < 4; ++cb) wf[kb][cb] = ldW(Wf, kb, cb, lane);
#pragma unroll
  for (int kb = 0; kb < 2; ++kb)
#pragma unroll
    for (int cb = 0; cb < 4; ++cb) wn[kb][cb] = ldW(Wn, kb, cb, lane);
  float bv[4], bnv[4];
#pragma unroll
  for (int cb = 0; cb < 4; ++cb){ bv[cb] = bias[cb*16 + (lane & 15)]; bnv[cb] = bn[cb*16 + (lane & 15)]; }
  const long ra = (R + (lane & 15) < N) ? (R + (lane & 15)) : (N - 1);
  f4v acc[4] = {f4v{0,0,0,0}, f4v{0,0,0,0}, f4v{0,0,0,0}, f4v{0,0,0,0}};
#pragma unroll
  for (int kb = 0; kb < 4; ++kb){
    bfrag a = (kb < 2) ? ldA(A1, ra, kb*32, lane) : ldA(A2, ra, (kb-2)*32, lane);
#pragma unroll
    for (int cb = 0; cb < 4; ++cb) acc[cb] = MFMA(a, wf[kb][cb], acc[cb]);
  }
#pragma unroll
  for (int cb = 0; cb < 4; ++cb)
#pragma unroll
    for (int j = 0; j < 4; ++j) acc[cb][j] += bv[cb];
  const int rbase = R + ((lane >> 4) << 2), cl = lane & 15;
#pragma unroll
  for (int cb = 0; cb < 4; ++cb)
#pragma unroll
    for (int j = 0; j < 4; ++j){
      int r = rbase + j;
      if (r < N) out[(size_t)r*64 + cb*16 + cl] = f2bf(acc[cb][j]);
    }
  // fused x_nl for next layer
  xpose_store(sT[w], lane, acc);
  f4v ac2[4] = {f4v{0,0,0,0}, f4v{0,0,0,0}, f4v{0,0,0,0}, f4v{0,0,0,0}};
#pragma unroll
  for (int kb = 0; kb < 2; ++kb){
    bfrag a = xpose_load(sT[w], lane, kb);
#pragma unroll
    for (int cb = 0; cb < 4; ++cb) ac2[cb] = MFMA(a, wn[kb][cb], ac2[cb]);
  }
#pragma unroll
  for (int cb = 0; cb < 4; ++cb)
#pragma unroll
    for (int j = 0; j < 4; ++j){
      int r = rbase + j;
      if (r < N) xnl[(size_t)r*64 + cb*16 + cl] = f2bf(ac2[cb][j] + bnv[cb]);
    }
}

// ---------------- GEMM layer-agg: K=320, W streamed per-kb (low VGPR) ----------------
__global__ __launch_bounds__(256) void gemmL_k(const u16* __restrict__ e0,
    const u16* __restrict__ e1, const u16* __restrict__ e2, const u16* __restrict__ e3,
    const u16* __restrict__ Wf, const float* __restrict__ bias,
    u16* __restrict__ out, int N){
  const int lane = threadIdx.x & 63, w = threadIdx.x >> 6;
  const int R = blockIdx.x*64 + w*16;
  const u16* Ab[4] = {e0, e1, e2, e3};
  float bv[4];
#pragma unroll
  for (int cb = 0; cb < 4; ++cb) bv[cb] = bias[cb*16 + (lane & 15)];
  const long ra = (R + (lane & 15) < N) ? (R + (lane & 15)) : (N - 1);
  f4v acc[4] = {f4v{0,0,0,0}, f4v{0,0,0,0}, f4v{0,0,0,0}, f4v{0,0,0,0}};
  bfrag mx[2];
#pragma unroll
  for (int kb = 0; kb < 8; ++kb){
    bfrag a = ldA(Ab[kb >> 1], ra, (kb & 1)*32, lane);
    if (kb < 2){ mx[kb] = a; }
    else {
      bfrag& m = mx[kb & 1];
#pragma unroll
      for (int i = 0; i < 8; ++i)
        m[i] = (short)f2bf(fmaxf(bf2f((u16)m[i]), bf2f((u16)a[i])));
    }
#pragma unroll
    for (int cb = 0; cb < 4; ++cb) acc[cb] = MFMA(a, ldW(Wf, kb, cb, lane), acc[cb]);
  }
#pragma unroll
  for (int kb = 8; kb < 10; ++kb)
#pragma unroll
    for (int cb = 0; cb < 4; ++cb) acc[cb] = MFMA(mx[kb-8], ldW(Wf, kb, cb, lane), acc[cb]);
  const int rbase = R + ((lane >> 4) << 2), cl = lane & 15;
#pragma unroll
  for (int cb = 0; cb < 4; ++cb)
#pragma unroll
    for (int j = 0; j < 4; ++j){
      int r = rbase + j;
      if (r < N) out[(size_t)r*64 + cb*16 + cl] = f2bf(acc[cb][j] + bv[cb]);
    }
}

// ---------------- fused feed-forward head: relu(mix@W1+b1)@W2 + b2 -> fp32 out ----------------
__global__ __launch_bounds__(256) void ff12_k(const u16* __restrict__ A,
    const u16* __restrict__ Wf1, const float* __restrict__ b1,
    const u16* __restrict__ Wf2, const float* __restrict__ b2,
    float* __restrict__ out, int N){
  __shared__ u16 sT[4][1024];
  const int lane = threadIdx.x & 63, w = threadIdx.x >> 6;
  const int R = blockIdx.x*64 + w*16;
  bfrag wf1[2][4], wf2[2][4];
#pragma unroll
  for (int kb = 0; kb < 2; ++kb)
#pragma unroll
    for (int cb = 0; cb < 4; ++cb){ wf1[kb][cb] = ldW(Wf1, kb, cb, lane); wf2[kb][cb] = ldW(Wf2, kb, cb, lane); }
  float bv1[4], bv2[4];
#pragma unroll
  for (int cb = 0; cb < 4; ++cb){ bv1[cb] = b1[cb*16 + (lane & 15)]; bv2[cb] = b2[cb*16 + (lane & 15)]; }
  const long ra = (R + (lane & 15) < N) ? (R + (lane & 15)) : (N - 1);
  f4v acc[4] = {f4v{0,0,0,0}, f4v{0,0,0,0}, f4v{0,0,0,0}, f4v{0,0,0,0}};
#pragma unroll
  for (int kb = 0; kb < 2; ++kb){
    bfrag a = ldA(A, ra, kb*32, lane);
#pragma unroll
    for (int cb = 0; cb < 4; ++cb) acc[cb] = MFMA(a, wf1[kb][cb], acc[cb]);
  }
#pragma unroll
  for (int cb = 0; cb < 4; ++cb)
#pragma unroll
    for (int j = 0; j < 4; ++j) acc[cb][j] = fmaxf(acc[cb][j] + bv1[cb], 0.f);
  xpose_store(sT[w], lane, acc);
  f4v ac2[4] = {f4v{0,0,0,0}, f4v{0,0,0,0}, f4v{0,0,0,0}, f4v{0,0,0,0}};
#pragma unroll
  for (int kb = 0; kb < 2; ++kb){
    bfrag a = xpose_load(sT[w], lane, kb);
#pragma unroll
    for (int cb = 0; cb < 4; ++cb) ac2[cb] = MFMA(a, wf2[kb][cb], ac2[cb]);
  }
  const int rbase = R + ((lane >> 4) << 2), cl = lane & 15;
#pragma unroll
  for (int cb = 0; cb < 4; ++cb)
#pragma unroll
    for (int j = 0; j < 4; ++j){
      int r = rbase + j;
      if (r < N) out[(size_t)r*64 + cb*16 + cl] = ac2[cb][j] + bv2[cb];
    }
}

// ---------------- neighbor aggregate: 16 rows/wave (2 per lane-group), 2x MLP ----------------
__global__ __launch_bounds__(256) void gather_k(const u16* __restrict__ xnl,
    const int* __restrict__ off, const int* __restrict__ cnt, const int* __restrict__ perm,
    const float* __restrict__ Z_agg, int layer, u16* __restrict__ xn, int N){
  const int lane = threadIdx.x & 63, w = threadIdx.x >> 6;
  const int g = lane >> 3;            // row slot (0..7)
  const int q = lane & 7;             // channel octet
  const int gbase = lane & 56;
  const int rA = blockIdx.x*64 + w*16 + g;
  const int rB = rA + 8;
  const float za0 = Z_agg[layer*3+0], za1 = Z_agg[layer*3+1], za2 = Z_agg[layer*3+2];
  int eA = 0, dA = 0, eB = 0, dB = 0;
  if (rA < N){ eA = off[rA]; dA = cnt[rA]; }
  if (rB < N){ eB = off[rB]; dB = cnt[rB]; }
  const float NI = -3.402823466e38f;
  float sA0=0.f,sA1=0.f,sA2=0.f,sA3=0.f,sA4=0.f,sA5=0.f,sA6=0.f,sA7=0.f;
  float mA0=NI,mA1=NI,mA2=NI,mA3=NI,mA4=NI,mA5=NI,mA6=NI,mA7=NI;
  float sB0=0.f,sB1=0.f,sB2=0.f,sB3=0.f,sB4=0.f,sB5=0.f,sB6=0.f,sB7=0.f;
  float mB0=NI,mB1=NI,mB2=NI,mB3=NI,mB4=NI,mB5=NI,mB6=NI,mB7=NI;
  const u16* xq = xnl + q*8;          // lane's channel-octet base
  const int dmax = (dA > dB) ? dA : dB;
  for (int base = 0; base < dmax; base += 8){
    int peA = (base + q < dA) ? perm[eA + base + q] : 0;
    int peB = (base + q < dB) ? perm[eB + base + q] : 0;
#pragma unroll
    for (int j = 0; j < 8; ++j){
      int sAi = __shfl(peA, gbase + j, 64);
      int sBi = __shfl(peB, gbase + j, 64);
      if (base + j < dA){
        uint4 u = *reinterpret_cast<const uint4*>(xq + ((size_t)sAi << 6));
        float a0 = __uint_as_float(u.x << 16), a1 = __uint_as_float(u.x & 0xffff0000u);
        float a2 = __uint_as_float(u.y << 16), a3 = __uint_as_float(u.y & 0xffff0000u);
        float a4 = __uint_as_float(u.z << 16), a5 = __uint_as_float(u.z & 0xffff0000u);
        float a6 = __uint_as_float(u.w << 16), a7 = __uint_as_float(u.w & 0xffff0000u);
        sA0 += a0; sA1 += a1; sA2 += a2; sA3 += a3;
        sA4 += a4; sA5 += a5; sA6 += a6; sA7 += a7;
        mA0 = fmaxf(mA0, a0); mA1 = fmaxf(mA1, a1); mA2 = fmaxf(mA2, a2); mA3 = fmaxf(mA3, a3);
        mA4 = fmaxf(mA4, a4); mA5 = fmaxf(mA5, a5); mA6 = fmaxf(mA6, a6); mA7 = fmaxf(mA7, a7);
      }
      if (base + j < dB){
        uint4 u = *reinterpret_cast<const uint4*>(xq + ((size_t)sBi << 6));
        float a0 = __uint_as_float(u.x << 16), a1 = __uint_as_float(u.x & 0xffff0000u);
        float a2 = __uint_as_float(u.y << 16), a3 = __uint_as_float(u.y & 0xffff0000u);
        float a4 = __uint_as_float(u.z << 16), a5 = __uint_as_float(u.z & 0xffff0000u);
        float a6 = __uint_as_float(u.w << 16), a7 = __uint_as_float(u.w & 0xffff0000u);
        sB0 += a0; sB1 += a1; sB2 += a2; sB3 += a3;
        sB4 += a4; sB5 += a5; sB6 += a6; sB7 += a7;
        mB0 = fmaxf(mB0, a0); mB1 = fmaxf(mB1, a1); mB2 = fmaxf(mB2, a2); mB3 = fmaxf(mB3, a3);
        mB4 = fmaxf(mB4, a4); mB5 = fmaxf(mB5, a5); mB6 = fmaxf(mB6, a6); mB7 = fmaxf(mB7, a7);
      }
    }
  }
  if (rA < N){
    const float inv = 1.f / fmaxf((float)dA, 1.f);
    const float gz = (dA > 0) ? 1.f : 0.f;
    const float ca = za0 + za1*inv, cm = za2*gz;
    uint4 o;
    o.x = (u32)f2bf(ca*sA0 + cm*mA0) | (((u32)f2bf(ca*sA1 + cm*mA1)) << 16);
    o.y = (u32)f2bf(ca*sA2 + cm*mA2) | (((u32)f2bf(ca*sA3 + cm*mA3)) << 16);
    o.z = (u32)f2bf(ca*sA4 + cm*mA4) | (((u32)f2bf(ca*sA5 + cm*mA5)) << 16);
    o.w = (u32)f2bf(ca*sA6 + cm*mA6) | (((u32)f2bf(ca*sA7 + cm*mA7)) << 16);
    reinterpret_cast<uint4*>(xn + ((size_t)rA << 6))[q] = o;
  }
  if (rB < N){
    const float inv = 1.f / fmaxf((float)dB, 1.f);
    const float gz = (dB > 0) ? 1.f : 0.f;
    const float ca = za0 + za1*inv, cm = za2*gz;
    uint4 o;
    o.x = (u32)f2bf(ca*sB0 + cm*mB0) | (((u32)f2bf(ca*sB1 + cm*mB1)) << 16);
    o.y = (u32)f2bf(ca*sB2 + cm*mB2) | (((u32)f2bf(ca*sB3 + cm*mB3)) << 16);
    o.z = (u32)f2bf(ca*sB4 + cm*mB4) | (((u32)f2bf(ca*sB5 + cm*mB5)) << 16);
    o.w = (u32)f2bf(ca*sB6 + cm*mB6) | (((u32)f2bf(ca*sB7 + cm*mB7)) << 16);
    reinterpret_cast<uint4*>(xn + ((size_t)rB << 6))[q] = o;
  }
}

extern "C" void kernel_launch(void* const* d_in, const int* in_sizes, int n_in,
                              void* d_out, int out_size, void* d_ws, size_t ws_size,
                              hipStream_t stream){
  const float* x      = (const float*)d_in[0];
  const int*   ei     = (const int*)  d_in[1];
  const float* W_pre  = (const float*)d_in[2];
  const float* b_pre  = (const float*)d_in[3];
  const float* W_self = (const float*)d_in[4];
  const float* b_self = (const float*)d_in[5];
  const float* W_nbr  = (const float*)d_in[6];
  const float* b_nbr  = (const float*)d_in[7];
  const float* W_comb = (const float*)d_in[8];
  const float* b_comb = (const float*)d_in[9];
  const float* W_lc   = (const float*)d_in[10];
  const float* b_lc   = (const float*)d_in[11];
  const float* ln_g   = (const float*)d_in[12];
  const float* ln_b   = (const float*)d_in[13];
  const float* prelu  = (const float*)d_in[14];
  const float* W_lagg = (const float*)d_in[15];
  const float* b_lagg = (const float*)d_in[16];
  const float* W_ff1  = (const float*)d_in[17];
  const float* b_ff1  = (const float*)d_in[18];
  const float* W_ff2  = (const float*)d_in[19];
  const float* b_ff2  = (const float*)d_in[20];
  const float* Z_agg  = (const float*)d_in[21];
  const float* Z_comb = (const float*)d_in[22];
  const float* Z_act  = (const float*)d_in[23];
  const float* Z_lc   = (const float*)d_in[24];
  const float* Z_lagg = (const float*)d_in[25];

  const int N = in_sizes[0] / 128;
  const int E = in_sizes[1] / 2;
  const int* src = ei;
  const int* tgt = ei + E;

  const int nch = DIV_UP(N, CHB);
  const int bstride = (int)(((long)E * CHB) / N) + 2048;

  char* p = (char*)d_ws;
  auto carve = [&](size_t bytes)->void*{
    void* q = (void*)p;
    p += (bytes + 255) & ~(size_t)255;
    return q;
  };
  int* cnt_i = (int*)carve((size_t)N*4);
  int* off   = (int*)carve((size_t)N*4);
  int* bktCnt= (int*)carve(NBKT*4);
  int2* bkt  = (int2*)carve((size_t)NBKT*bstride*8);
  int* perm  = (int*)carve((size_t)NBKT*bstride*4);
  float* WsWct = (float*)carve(3*4096*4);
  float* bsWct = (float*)carve(3*64*4);
  float* W1eff = (float*)carve(3*4096*4);
  float* W2eff = (float*)carve(3*4096*4);
  float* beff  = (float*)carve(3*64*4);
  float* Wlceff= (float*)carve(2*8192*4);
  float* blceff= (float*)carve(2*64*4);
  float* Wle   = (float*)carve(20480*4);
  float* ble   = (float*)carve(64*4);
  u16* pWpre = (u16*)carve(8192*2);
  u16* pWnbr = (u16*)carve(3*4096*2);
  u16* pW1   = (u16*)carve(3*4096*2);
  u16* pW2   = (u16*)carve(3*4096*2);
  u16* pWlc  = (u16*)carve(2*8192*2);
  u16* pWlagg= (u16*)carve(20480*2);
  u16* pWff1 = (u16*)carve(4096*2);
  u16* pWff2 = (u16*)carve(4096*2);
  const size_t AB = (size_t)N*64*2;
  u16* emb0 = (u16*)carve(AB);
  u16* emb1 = (u16*)carve(AB);
  u16* emb2 = (u16*)carve(AB);
  u16* emb3 = (u16*)carve(AB);
  u16* xbuf = (u16*)carve(AB);
  u16* xnl  = (u16*)carve(AB);
  u16* xn   = (u16*)carve(AB);
  u16* mixb = (u16*)carve(AB);

  // ---- CSR build: 256-bucket partition, then per-chunk LDS counting sort ----
  initBkt_k<<<1,NBKT,0,stream>>>(bktCnt, bstride);
  partition_k<<<DIV_UP(E,PTILE),NBKT,0,stream>>>(tgt, src, E, bktCnt, bkt);
  sortChunk_k<<<nch,CHB,0,stream>>>(bkt, bktCnt, bstride, N, cnt_i, off, perm);

  // ---- weight prep ----
  matW_k<<<3*65,64,0,stream>>>(W_self, W_comb, b_self, WsWct, bsWct);
  buildAll_k<<<DIV_UP(49536,256),256,0,stream>>>(W_self, W_comb, b_self, b_comb, Z_comb,
                                                 WsWct, bsWct, W_lc, b_lc, Z_lc,
                                                 W_lagg, b_lagg, Z_lagg,
                                                 W1eff, W2eff, beff, Wlceff, blceff, Wle, ble);

  PackJobs pj;
  pj.src[0] = W_pre;  pj.dst[0] = pWpre;  pj.nkb[0] = 4;
  for (int i = 0; i < 3; ++i){
    pj.src[1+i] = W_nbr + i*4096; pj.dst[1+i] = pWnbr + i*4096; pj.nkb[1+i] = 2;
    pj.src[4+i] = W1eff + i*4096; pj.dst[4+i] = pW1   + i*4096; pj.nkb[4+i] = 2;
    pj.src[7+i] = W2eff + i*4096; pj.dst[7+i] = pW2   + i*4096; pj.nkb[7+i] = 2;
  }
  pj.src[10] = Wlceff;        pj.dst[10] = pWlc;        pj.nkb[10] = 4;
  pj.src[11] = Wlceff + 8192; pj.dst[11] = pWlc + 8192; pj.nkb[11] = 4;
  pj.src[12] = Wle;   pj.dst[12] = pWlagg; pj.nkb[12] = 10;
  pj.src[13] = W_ff1; pj.dst[13] = pWff1;  pj.nkb[13] = 2;
  pj.src[14] = W_ff2; pj.dst[14] = pWff2;  pj.nkb[14] = 2;
  pack_all_k<<<15*16,256,0,stream>>>(pj);

  const int G64 = DIV_UP(N, 64);

  // ---- preprocess (+ fused x_nl layer 0) ----
  gemmP_k<<<G64,256,0,stream>>>(x, pWpre, b_pre, pWnbr, b_nbr, emb0, xnl, N);

  // ---- layers ----
  u16* embs[4] = {emb0, emb1, emb2, emb3};
  const u16* xin = emb0;
  for (int i = 0; i < 3; ++i){
    gather_k<<<G64,256,0,stream>>>(xnl, off, cnt_i, perm, Z_agg, i, xn, N);
    gemmC_k<<<G64,256,0,stream>>>(xin, xn, pW1 + i*4096, pW2 + i*4096,
                                  beff + i*64, ln_g + i*64, ln_b + i*64,
                                  Z_act + i*2, prelu + i, embs[i+1], N);
    if (i < 2){
      lc_k<<<G64,256,0,stream>>>(embs[i], embs[i+1], pWlc + i*8192, blceff + i*64,
                                 pWnbr + (i+1)*4096, b_nbr + (i+1)*64, xbuf, xnl, N);
      xin = xbuf;
    }
  }

  // ---- layer agg (max folded in via zg1*I weight rows) + head ----
  gemmL_k<<<G64,256,0,stream>>>(emb0, emb1, emb2, emb3, pWlagg, ble, mixb, N);
  ff12_k<<<G64,256,0,stream>>>(mixb, pWff1, b_ff1, pWff2, b_ff2, (float*)d_out, N);
}

// Round 9
// 268.467 us; speedup vs baseline: 1.0776x; 1.0776x over previous
//
#include <hip/hip_runtime.h>

typedef unsigned short u16;
typedef unsigned int u32;
using bfrag = __attribute__((ext_vector_type(8))) short;
using f4v   = __attribute__((ext_vector_type(4))) float;

#define DIV_UP(a,b) (((a)+(b)-1)/(b))
#define PTILE 4096
#define CHB 512
#define CHSH 9
#define NBKT 256
#define MFMA(a,b,c) __builtin_amdgcn_mfma_f32_16x16x32_bf16(a,b,c,0,0,0)

__device__ inline u16 f2bf(float f){
  union { float f; u32 u; } v; v.f = f;
  u32 u = v.u;
  return (u16)((u + 0x7fffu + ((u >> 16) & 1u)) >> 16);
}
__device__ inline float bf2f(u16 h){
  union { u32 u; float f; } v; v.u = ((u32)h) << 16;
  return v.f;
}
__device__ inline bfrag ldA(const u16* A, long r, int koff, int lane){
  return *reinterpret_cast<const bfrag*>(A + r*64 + koff + ((lane>>4)<<3));
}
__device__ inline bfrag ldW(const u16* Wf, int kb, int cb, int lane){
  return *reinterpret_cast<const bfrag*>(Wf + (((kb*4+cb)*64 + lane)<<3));
}

// --- per-wave 16x64 C-tile -> A-fragment transpose via swizzled LDS (no barrier) ---
__device__ inline void xpose_store(u16* sT, int lane, const f4v (&acc)[4]){
  const int cl = lane & 15, g = lane >> 4;
#pragma unroll
  for (int j = 0; j < 4; ++j){
    const int lr = g*4 + j;
#pragma unroll
    for (int cb = 0; cb < 4; ++cb){
      const int colblk = cb*2 + (cl >> 3);
      const int gr = colblk ^ (lr & 7);
      sT[lr*64 + gr*8 + (cl & 7)] = f2bf(acc[cb][j]);
    }
  }
}
__device__ inline bfrag xpose_load(const u16* sT, int lane, int kb){
  const int row = lane & 15, colblk = kb*4 + (lane >> 4);
  const int gr = colblk ^ (row & 7);
  return *reinterpret_cast<const bfrag*>(sT + row*64 + gr*8);
}

// ---------------- edge radix-partition into 256 target-chunk buckets ----------------
__global__ void initBkt_k(int* __restrict__ bktCnt, int bstride){
  if (threadIdx.x < NBKT) bktCnt[threadIdx.x] = threadIdx.x * bstride;
}
__global__ void partition_k(const int* __restrict__ tgt, const int* __restrict__ src,
                            int E, int* __restrict__ bktCnt, int2* __restrict__ bkt){
  __shared__ int hist[NBKT], base[NBKT], pos[NBKT];
  const int t = threadIdx.x;
  hist[t] = 0;
  __syncthreads();
  const int e0 = blockIdx.x * PTILE;
  const int e1 = (e0 + PTILE < E) ? e0 + PTILE : E;
  for (int i = e0 + t; i < e1; i += NBKT)
    atomicAdd(&hist[tgt[i] >> CHSH], 1);
  __syncthreads();
  base[t] = (hist[t] > 0) ? atomicAdd(&bktCnt[t], hist[t]) : 0;
  pos[t] = 0;
  __syncthreads();
  for (int i = e0 + t; i < e1; i += NBKT){
    int tv = tgt[i], sv = src[i];
    int c = tv >> CHSH;
    int p = base[c] + atomicAdd(&pos[c], 1);
    bkt[p] = make_int2(tv, sv);
  }
}

// ---------------- per-chunk LDS counting sort: one workgroup per chunk ----------------
__global__ __launch_bounds__(CHB) void sortChunk_k(const int2* __restrict__ bkt,
    const int* __restrict__ bktCnt, int bstride, int N,
    int* __restrict__ cnt, int* __restrict__ off, int* __restrict__ perm){
  __shared__ int hist[CHB], sbase[CHB];
  const int c = blockIdx.x, t = threadIdx.x;
  const int lo = c * CHB;
  const int s = c * bstride, e = bktCnt[c];
  hist[t] = 0;
  __syncthreads();
  for (int i = s + t; i < e; i += CHB)
    atomicAdd(&hist[bkt[i].x - lo], 1);
  __syncthreads();
  const int v = hist[t];
  for (int o = 1; o < CHB; o <<= 1){
    int add = (t >= o) ? hist[t - o] : 0;
    __syncthreads();
    hist[t] += add;
    __syncthreads();
  }
  const int excl = hist[t] - v;
  if (lo + t < N){ cnt[lo + t] = v; off[lo + t] = s + excl; }
  sbase[t] = s + excl;
  __syncthreads();
  hist[t] = 0;
  __syncthreads();
  for (int i = s + t; i < e; i += CHB){
    int2 ed = bkt[i];
    int r = ed.x - lo;
    int p = sbase[r] + atomicAdd(&hist[r], 1);
    perm[p] = ed.y;
  }
}

// ---------------- weight prep: one block per output row (195x64) ----------------
__global__ void matW_k(const float* __restrict__ W_self, const float* __restrict__ W_comb,
                       const float* __restrict__ b_self,
                       float* __restrict__ WsWct, float* __restrict__ bsWct){
  const int b = blockIdx.x;
  const int i = b / 65, r = b % 65;
  const int c = threadIdx.x;
  const float* Wc = W_comb + i*8192;
  float s = 0.f;
  if (r < 64){
    const float* a = W_self + i*4096 + r*64;
#pragma unroll 8
    for (int k = 0; k < 64; ++k) s += a[k] * Wc[k*64 + c];
    WsWct[i*4096 + r*64 + c] = s;
  } else {
    const float* a = b_self + i*64;
#pragma unroll 8
    for (int k = 0; k < 64; ++k) s += a[k] * Wc[k*64 + c];
    bsWct[i*64 + c] = s;
  }
}

// ---------------- all effective-weight builds in one grid-strided kernel ----------------
// Wle is 320x64: rows 0..255 = zg2*W_lagg (+ zg0*I at 192..255), rows 256..319 = zg1*I
__global__ void buildAll_k(const float* __restrict__ W_self, const float* __restrict__ W_comb,
    const float* __restrict__ b_self, const float* __restrict__ b_comb,
    const float* __restrict__ Z_comb, const float* __restrict__ WsWct,
    const float* __restrict__ bsWct,
    const float* __restrict__ W_lc, const float* __restrict__ b_lc,
    const float* __restrict__ Z_lc,
    const float* __restrict__ W_lagg, const float* __restrict__ b_lagg,
    const float* __restrict__ Z_lagg,
    float* __restrict__ W1eff, float* __restrict__ W2eff, float* __restrict__ beff,
    float* __restrict__ Wlceff, float* __restrict__ blceff,
    float* __restrict__ Wle, float* __restrict__ ble){
  int idx = blockIdx.x*blockDim.x + threadIdx.x;
  if (idx < 12288){
    int i = idx >> 12, rem = idx & 4095, k = rem >> 6, c = rem & 63;
    float zc0 = Z_comb[i*2], zc1 = Z_comb[i*2+1];
    W1eff[idx] = zc0*W_self[idx] + zc1*WsWct[idx];
    W2eff[idx] = (k == c ? zc0 : 0.f) + zc1*W_comb[i*8192 + (64 + k)*64 + c];
    return;
  }
  idx -= 12288;
  if (idx < 16384){
    int i = idx >> 13, rem = idx & 8191, k = rem >> 6, c = rem & 63;
    float z0 = Z_lc[i*3], z1 = Z_lc[i*3+1], z2 = Z_lc[i*3+2];
    float idv = (k < 64) ? (k == c ? z1 : 0.f) : ((k - 64) == c ? (z0 + z1) : 0.f);
    Wlceff[idx] = z2*W_lc[idx] + idv;
    return;
  }
  idx -= 16384;
  if (idx < 20480){
    int k = idx >> 6, c = idx & 63;
    float v = (k < 256) ? Z_lagg[2]*W_lagg[idx] : 0.f;
    if (k >= 192 && k < 256 && (k - 192) == c) v += Z_lagg[0];
    if (k >= 256 && (k - 256) == c) v += Z_lagg[1];
    Wle[idx] = v;
    return;
  }
  idx -= 20480;
  if (idx < 192){
    int i = idx >> 6;
    float zc0 = Z_comb[i*2], zc1 = Z_comb[i*2+1];
    beff[idx] = zc0*b_self[idx] + zc1*(bsWct[idx] + b_comb[idx]);
    return;
  }
  idx -= 192;
  if (idx < 128){
    int i = idx >> 6;
    blceff[idx] = Z_lc[i*3+2]*b_lc[idx];
    return;
  }
  idx -= 128;
  if (idx < 64) ble[idx] = Z_lagg[2]*b_lagg[idx];
}

// ---------------- pack fp32 [K][64] -> bf16 MFMA B-fragment layout ----------------
struct PackJobs {
  const float* src[15];
  u16* dst[15];
  int nkb[15];
};
__global__ void pack_all_k(PackJobs pj){
  const int job = blockIdx.x >> 4, kb = blockIdx.x & 15;
  if (kb >= pj.nkb[job]) return;
  const int t = threadIdx.x, cb = t >> 6, lane = t & 63;
  const float* S = pj.src[job];
  u16* D = pj.dst[job] + (((kb*4 + cb)*64 + lane) << 3);
  const int kbase = kb*32 + ((lane >> 4) << 3), c = cb*16 + (lane & 15);
#pragma unroll
  for (int j = 0; j < 8; ++j) D[j] = f2bf(S[(kbase + j)*64 + c]);
}

// ---------------- GEMM pre: fp32 A [N][128] -> emb0, fused xnl0 = emb0@Wnbr0 + bnbr0 ----------------
__global__ __launch_bounds__(256) void gemmP_k(const float* __restrict__ X,
    const u16* __restrict__ Wf, const float* __restrict__ bias,
    const u16* __restrict__ Wn, const float* __restrict__ bn,
    u16* __restrict__ out, u16* __restrict__ xnl, int N){
  __shared__ u16 sT[4][1024];
  const int lane = threadIdx.x & 63, w = threadIdx.x >> 6;
  const int R = blockIdx.x*64 + w*16;
  bfrag wf[4][4], wn[2][4];
#pragma unroll
  for (int kb = 0; kb < 4; ++kb)
#pragma unroll
    for (int cb = 0; cb < 4; ++cb) wf[kb][cb] = ldW(Wf, kb, cb, lane);
#pragma unroll
  for (int kb = 0; kb < 2; ++kb)
#pragma unroll
    for (int cb = 0; cb < 4; ++cb) wn[kb][cb] = ldW(Wn, kb, cb, lane);
  float bv[4], bnv[4];
#pragma unroll
  for (int cb = 0; cb < 4; ++cb){ bv[cb] = bias[cb*16 + (lane & 15)]; bnv[cb] = bn[cb*16 + (lane & 15)]; }
  const long ra = (R + (lane & 15) < N) ? (R + (lane & 15)) : (N - 1);
  f4v acc[4] = {f4v{0,0,0,0}, f4v{0,0,0,0}, f4v{0,0,0,0}, f4v{0,0,0,0}};
#pragma unroll
  for (int kb = 0; kb < 4; ++kb){
    const float* ap = X + ra*128 + kb*32 + ((lane >> 4) << 3);
    float4 q0 = *reinterpret_cast<const float4*>(ap);
    float4 q1 = *reinterpret_cast<const float4*>(ap + 4);
    bfrag a;
    a[0] = (short)f2bf(q0.x); a[1] = (short)f2bf(q0.y);
    a[2] = (short)f2bf(q0.z); a[3] = (short)f2bf(q0.w);
    a[4] = (short)f2bf(q1.x); a[5] = (short)f2bf(q1.y);
    a[6] = (short)f2bf(q1.z); a[7] = (short)f2bf(q1.w);
#pragma unroll
    for (int cb = 0; cb < 4; ++cb) acc[cb] = MFMA(a, wf[kb][cb], acc[cb]);
  }
#pragma unroll
  for (int cb = 0; cb < 4; ++cb)
#pragma unroll
    for (int j = 0; j < 4; ++j) acc[cb][j] += bv[cb];
  const int rbase = R + ((lane >> 4) << 2), cl = lane & 15;
#pragma unroll
  for (int cb = 0; cb < 4; ++cb)
#pragma unroll
    for (int j = 0; j < 4; ++j){
      int r = rbase + j;
      if (r < N) out[(size_t)r*64 + cb*16 + cl] = f2bf(acc[cb][j]);
    }
  // fused x_nl0
  xpose_store(sT[w], lane, acc);
  f4v ac2[4] = {f4v{0,0,0,0}, f4v{0,0,0,0}, f4v{0,0,0,0}, f4v{0,0,0,0}};
#pragma unroll
  for (int kb = 0; kb < 2; ++kb){
    bfrag a = xpose_load(sT[w], lane, kb);
#pragma unroll
    for (int cb = 0; cb < 4; ++cb) ac2[cb] = MFMA(a, wn[kb][cb], ac2[cb]);
  }
#pragma unroll
  for (int cb = 0; cb < 4; ++cb)
#pragma unroll
    for (int j = 0; j < 4; ++j){
      int r = rbase + j;
      if (r < N) xnl[(size_t)r*64 + cb*16 + cl] = f2bf(ac2[cb][j] + bnv[cb]);
    }
}

// ---------------- GEMM combine only (last layer): h -> emb_out ----------------
__global__ __launch_bounds__(256) void gemmC_k(const u16* __restrict__ A1,
    const u16* __restrict__ A2, const u16* __restrict__ Wf1, const u16* __restrict__ Wf2,
    const float* __restrict__ beff, const float* __restrict__ lng, const float* __restrict__ lnb,
    const float* __restrict__ Zact, const float* __restrict__ prelu,
    u16* __restrict__ out, int N){
  const int lane = threadIdx.x & 63, w = threadIdx.x >> 6;
  const int R = blockIdx.x*64 + w*16;
  bfrag wf1[2][4], wf2[2][4];
#pragma unroll
  for (int kb = 0; kb < 2; ++kb)
#pragma unroll
    for (int cb = 0; cb < 4; ++cb){ wf1[kb][cb] = ldW(Wf1, kb, cb, lane); wf2[kb][cb] = ldW(Wf2, kb, cb, lane); }
  float bv[4], lgv[4], lbv[4];
#pragma unroll
  for (int cb = 0; cb < 4; ++cb){
    int c = cb*16 + (lane & 15);
    bv[cb] = beff[c]; lgv[cb] = lng[c]; lbv[cb] = lnb[c];
  }
  const float zt0 = Zact[0], zt1 = Zact[1], pw = prelu[0];
  const long ra = (R + (lane & 15) < N) ? (R + (lane & 15)) : (N - 1);
  f4v acc[4] = {f4v{0,0,0,0}, f4v{0,0,0,0}, f4v{0,0,0,0}, f4v{0,0,0,0}};
#pragma unroll
  for (int kb = 0; kb < 2; ++kb){
    bfrag a = ldA(A1, ra, kb*32, lane);
#pragma unroll
    for (int cb = 0; cb < 4; ++cb) acc[cb] = MFMA(a, wf1[kb][cb], acc[cb]);
  }
#pragma unroll
  for (int kb = 0; kb < 2; ++kb){
    bfrag a = ldA(A2, ra, kb*32, lane);
#pragma unroll
    for (int cb = 0; cb < 4; ++cb) acc[cb] = MFMA(a, wf2[kb][cb], acc[cb]);
  }
#pragma unroll
  for (int cb = 0; cb < 4; ++cb)
#pragma unroll
    for (int j = 0; j < 4; ++j){
      float v = acc[cb][j] + bv[cb];
      v = zt0*fmaxf(v, 0.f) + zt1*((v > 0.f) ? v : pw*v);
      acc[cb][j] = v;
    }
  const int rbase = R + ((lane >> 4) << 2), cl = lane & 15;
#pragma unroll
  for (int j = 0; j < 4; ++j){
    float s = acc[0][j] + acc[1][j] + acc[2][j] + acc[3][j];
    s += __shfl_xor(s, 1, 64); s += __shfl_xor(s, 2, 64);
    s += __shfl_xor(s, 4, 64); s += __shfl_xor(s, 8, 64);
    float mu = s * 0.015625f;
    float d0 = acc[0][j]-mu, d1 = acc[1][j]-mu, d2 = acc[2][j]-mu, d3 = acc[3][j]-mu;
    float q = d0*d0 + d1*d1 + d2*d2 + d3*d3;
    q += __shfl_xor(q, 1, 64); q += __shfl_xor(q, 2, 64);
    q += __shfl_xor(q, 4, 64); q += __shfl_xor(q, 8, 64);
    float sd = rsqrtf(q * 0.015625f + 1e-5f);
    int r = rbase + j;
    if (r < N){
      out[(size_t)r*64 +  0 + cl] = f2bf(d0*sd*lgv[0] + lbv[0]);
      out[(size_t)r*64 + 16 + cl] = f2bf(d1*sd*lgv[1] + lbv[1]);
      out[(size_t)r*64 + 32 + cl] = f2bf(d2*sd*lgv[2] + lbv[2]);
      out[(size_t)r*64 + 48 + cl] = f2bf(d3*sd*lgv[3] + lbv[3]);
    }
  }
}

// ---------------- fused layer: combine+act+LN -> emb_out, then lc -> x_out, then x_nl ----------------
__global__ __launch_bounds__(256) void gemmCL_k(const u16* __restrict__ A1,
    const u16* __restrict__ A2, const u16* __restrict__ Aprev,
    const u16* __restrict__ Wf1, const u16* __restrict__ Wf2,
    const float* __restrict__ beff, const float* __restrict__ lng, const float* __restrict__ lnb,
    const float* __restrict__ Zact, const float* __restrict__ prelu,
    const u16* __restrict__ Wlc, const float* __restrict__ blc,
    const u16* __restrict__ Wn, const float* __restrict__ bn,
    u16* __restrict__ emb_out, u16* __restrict__ x_out, u16* __restrict__ xnl, int N){
  __shared__ u16 sT[4][1024];
  const int lane = threadIdx.x & 63, w = threadIdx.x >> 6;
  const int R = blockIdx.x*64 + w*16;
  bfrag wf1[2][4], wf2[2][4];
#pragma unroll
  for (int kb = 0; kb < 2; ++kb)
#pragma unroll
    for (int cb = 0; cb < 4; ++cb){ wf1[kb][cb] = ldW(Wf1, kb, cb, lane); wf2[kb][cb] = ldW(Wf2, kb, cb, lane); }
  float bv[4], lgv[4], lbv[4], blcv[4], bnv[4];
#pragma unroll
  for (int cb = 0; cb < 4; ++cb){
    int c = cb*16 + (lane & 15);
    bv[cb] = beff[c]; lgv[cb] = lng[c]; lbv[cb] = lnb[c];
    blcv[cb] = blc[c]; bnv[cb] = bn[c];
  }
  const float zt0 = Zact[0], zt1 = Zact[1], pw = prelu[0];
  const long ra = (R + (lane & 15) < N) ? (R + (lane & 15)) : (N - 1);
  f4v acc[4] = {f4v{0,0,0,0}, f4v{0,0,0,0}, f4v{0,0,0,0}, f4v{0,0,0,0}};
#pragma unroll
  for (int kb = 0; kb < 2; ++kb){
    bfrag a = ldA(A1, ra, kb*32, lane);
#pragma unroll
    for (int cb = 0; cb < 4; ++cb) acc[cb] = MFMA(a, wf1[kb][cb], acc[cb]);
  }
#pragma unroll
  for (int kb = 0; kb < 2; ++kb){
    bfrag a = ldA(A2, ra, kb*32, lane);
#pragma unroll
    for (int cb = 0; cb < 4; ++cb) acc[cb] = MFMA(a, wf2[kb][cb], acc[cb]);
  }
#pragma unroll
  for (int cb = 0; cb < 4; ++cb)
#pragma unroll
    for (int j = 0; j < 4; ++j){
      float v = acc[cb][j] + bv[cb];
      v = zt0*fmaxf(v, 0.f) + zt1*((v > 0.f) ? v : pw*v);
      acc[cb][j] = v;
    }
  const int rbase = R + ((lane >> 4) << 2), cl = lane & 15;
#pragma unroll
  for (int j = 0; j < 4; ++j){
    float s = acc[0][j] + acc[1][j] + acc[2][j] + acc[3][j];
    s += __shfl_xor(s, 1, 64); s += __shfl_xor(s, 2, 64);
    s += __shfl_xor(s, 4, 64); s += __shfl_xor(s, 8, 64);
    float mu = s * 0.015625f;
    float d0 = acc[0][j]-mu, d1 = acc[1][j]-mu, d2 = acc[2][j]-mu, d3 = acc[3][j]-mu;
    float q = d0*d0 + d1*d1 + d2*d2 + d3*d3;
    q += __shfl_xor(q, 1, 64); q += __shfl_xor(q, 2, 64);
    q += __shfl_xor(q, 4, 64); q += __shfl_xor(q, 8, 64);
    float sd = rsqrtf(q * 0.015625f + 1e-5f);
    acc[0][j] = d0*sd*lgv[0] + lbv[0];
    acc[1][j] = d1*sd*lgv[1] + lbv[1];
    acc[2][j] = d2*sd*lgv[2] + lbv[2];
    acc[3][j] = d3*sd*lgv[3] + lbv[3];
    int r = rbase + j;
    if (r < N){
      emb_out[(size_t)r*64 +  0 + cl] = f2bf(acc[0][j]);
      emb_out[(size_t)r*64 + 16 + cl] = f2bf(acc[1][j]);
      emb_out[(size_t)r*64 + 32 + cl] = f2bf(acc[2][j]);
      emb_out[(size_t)r*64 + 48 + cl] = f2bf(acc[3][j]);
    }
  }
  // ---- stage 2: layer-connect, h consumed via xpose (K=128: [Aprev, h]) ----
  xpose_store(sT[w], lane, acc);
  f4v ac2[4] = {f4v{0,0,0,0}, f4v{0,0,0,0}, f4v{0,0,0,0}, f4v{0,0,0,0}};
#pragma unroll
  for (int kb = 0; kb < 4; ++kb){
    bfrag a = (kb < 2) ? ldA(Aprev, ra, kb*32, lane) : xpose_load(sT[w], lane, kb - 2);
#pragma unroll
    for (int cb = 0; cb < 4; ++cb) ac2[cb] = MFMA(a, ldW(Wlc, kb, cb, lane), ac2[cb]);
  }
#pragma unroll
  for (int cb = 0; cb < 4; ++cb)
#pragma unroll
    for (int j = 0; j < 4; ++j) ac2[cb][j] += blcv[cb];
#pragma unroll
  for (int cb = 0; cb < 4; ++cb)
#pragma unroll
    for (int j = 0; j < 4; ++j){
      int r = rbase + j;
      if (r < N) x_out[(size_t)r*64 + cb*16 + cl] = f2bf(ac2[cb][j]);
    }
  // ---- stage 3: next layer's x_nl = x_out @ Wn + bn ----
  xpose_store(sT[w], lane, ac2);
  f4v ac3[4] = {f4v{0,0,0,0}, f4v{0,0,0,0}, f4v{0,0,0,0}, f4v{0,0,0,0}};
#pragma unroll
  for (int kb = 0; kb < 2; ++kb){
    bfrag a = xpose_load(sT[w], lane, kb);
#pragma unroll
    for (int cb = 0; cb < 4; ++cb) ac3[cb] = MFMA(a, ldW(Wn, kb, cb, lane), ac3[cb]);
  }
#pragma unroll
  for (int cb = 0; cb < 4; ++cb)
#pragma unroll
    for (int j = 0; j < 4; ++j){
      int r = rbase + j;
      if (r < N) xnl[(size_t)r*64 + cb*16 + cl] = f2bf(ac3[cb][j] + bnv[cb]);
    }
}

// ---------------- GEMM layer-agg: K=320, W streamed per-kb (low VGPR) ----------------
__global__ __launch_bounds__(256) void gemmL_k(const u16* __restrict__ e0,
    const u16* __restrict__ e1, const u16* __restrict__ e2, const u16* __restrict__ e3,
    const u16* __restrict__ Wf, const float* __restrict__ bias,
    u16* __restrict__ out, int N){
  const int lane = threadIdx.x & 63, w = threadIdx.x >> 6;
  const int R = blockIdx.x*64 + w*16;
  const u16* Ab[4] = {e0, e1, e2, e3};
  float bv[4];
#pragma unroll
  for (int cb = 0; cb < 4; ++cb) bv[cb] = bias[cb*16 + (lane & 15)];
  const long ra = (R + (lane & 15) < N) ? (R + (lane & 15)) : (N - 1);
  f4v acc[4] = {f4v{0,0,0,0}, f4v{0,0,0,0}, f4v{0,0,0,0}, f4v{0,0,0,0}};
  bfrag mx[2];
#pragma unroll
  for (int kb = 0; kb < 8; ++kb){
    bfrag a = ldA(Ab[kb >> 1], ra, (kb & 1)*32, lane);
    if (kb < 2){ mx[kb] = a; }
    else {
      bfrag& m = mx[kb & 1];
#pragma unroll
      for (int i = 0; i < 8; ++i)
        m[i] = (short)f2bf(fmaxf(bf2f((u16)m[i]), bf2f((u16)a[i])));
    }
#pragma unroll
    for (int cb = 0; cb < 4; ++cb) acc[cb] = MFMA(a, ldW(Wf, kb, cb, lane), acc[cb]);
  }
#pragma unroll
  for (int kb = 8; kb < 10; ++kb)
#pragma unroll
    for (int cb = 0; cb < 4; ++cb) acc[cb] = MFMA(mx[kb-8], ldW(Wf, kb, cb, lane), acc[cb]);
  const int rbase = R + ((lane >> 4) << 2), cl = lane & 15;
#pragma unroll
  for (int cb = 0; cb < 4; ++cb)
#pragma unroll
    for (int j = 0; j < 4; ++j){
      int r = rbase + j;
      if (r < N) out[(size_t)r*64 + cb*16 + cl] = f2bf(acc[cb][j] + bv[cb]);
    }
}

// ---------------- fused feed-forward head: relu(mix@W1+b1)@W2 + b2 -> fp32 out ----------------
__global__ __launch_bounds__(256) void ff12_k(const u16* __restrict__ A,
    const u16* __restrict__ Wf1, const float* __restrict__ b1,
    const u16* __restrict__ Wf2, const float* __restrict__ b2,
    float* __restrict__ out, int N){
  __shared__ u16 sT[4][1024];
  const int lane = threadIdx.x & 63, w = threadIdx.x >> 6;
  const int R = blockIdx.x*64 + w*16;
  bfrag wf1[2][4], wf2[2][4];
#pragma unroll
  for (int kb = 0; kb < 2; ++kb)
#pragma unroll
    for (int cb = 0; cb < 4; ++cb){ wf1[kb][cb] = ldW(Wf1, kb, cb, lane); wf2[kb][cb] = ldW(Wf2, kb, cb, lane); }
  float bv1[4], bv2[4];
#pragma unroll
  for (int cb = 0; cb < 4; ++cb){ bv1[cb] = b1[cb*16 + (lane & 15)]; bv2[cb] = b2[cb*16 + (lane & 15)]; }
  const long ra = (R + (lane & 15) < N) ? (R + (lane & 15)) : (N - 1);
  f4v acc[4] = {f4v{0,0,0,0}, f4v{0,0,0,0}, f4v{0,0,0,0}, f4v{0,0,0,0}};
#pragma unroll
  for (int kb = 0; kb < 2; ++kb){
    bfrag a = ldA(A, ra, kb*32, lane);
#pragma unroll
    for (int cb = 0; cb < 4; ++cb) acc[cb] = MFMA(a, wf1[kb][cb], acc[cb]);
  }
#pragma unroll
  for (int cb = 0; cb < 4; ++cb)
#pragma unroll
    for (int j = 0; j < 4; ++j) acc[cb][j] = fmaxf(acc[cb][j] + bv1[cb], 0.f);
  xpose_store(sT[w], lane, acc);
  f4v ac2[4] = {f4v{0,0,0,0}, f4v{0,0,0,0}, f4v{0,0,0,0}, f4v{0,0,0,0}};
#pragma unroll
  for (int kb = 0; kb < 2; ++kb){
    bfrag a = xpose_load(sT[w], lane, kb);
#pragma unroll
    for (int cb = 0; cb < 4; ++cb) ac2[cb] = MFMA(a, wf2[kb][cb], ac2[cb]);
  }
  const int rbase = R + ((lane >> 4) << 2), cl = lane & 15;
#pragma unroll
  for (int cb = 0; cb < 4; ++cb)
#pragma unroll
    for (int j = 0; j < 4; ++j){
      int r = rbase + j;
      if (r < N) out[(size_t)r*64 + cb*16 + cl] = ac2[cb][j] + bv2[cb];
    }
}

// ---------------- neighbor aggregate: 8 rows/wave, explicit 8-deep load buffering ----------------
__global__ __launch_bounds__(256) void gather_k(const u16* __restrict__ xnl,
    const int* __restrict__ off, const int* __restrict__ cnt, const int* __restrict__ perm,
    const float* __restrict__ Z_agg, int layer, u16* __restrict__ xn, int N){
  const int lane = threadIdx.x & 63, w = threadIdx.x >> 6;
  const int g = lane >> 3;            // row slot (0..7)
  const int q = lane & 7;             // channel octet
  const int gbase = lane & 56;
  const int r = blockIdx.x*32 + w*8 + g;
  const float za0 = Z_agg[layer*3+0], za1 = Z_agg[layer*3+1], za2 = Z_agg[layer*3+2];
  int e0 = 0, deg = 0;
  if (r < N){ e0 = off[r]; deg = cnt[r]; }
  const float NI = -3.402823466e38f;
  float s0=0.f,s1=0.f,s2=0.f,s3=0.f,s4=0.f,s5=0.f,s6=0.f,s7=0.f;
  float m0=NI,m1=NI,m2=NI,m3=NI,m4=NI,m5=NI,m6=NI,m7=NI;
  const u16* xq = xnl + q*8;          // lane's channel-octet base
  int pe = (q < deg) ? perm[e0 + q] : 0;
  for (int base = 0; base < deg; base += 8){
    // prefetch next perm batch (independent of this batch's work)
    int pe_n = (base + 8 + q < deg) ? perm[e0 + base + 8 + q] : 0;
    int idx[8];
#pragma unroll
    for (int j = 0; j < 8; ++j) idx[j] = __shfl(pe, gbase + j, 64);
    // issue all 8 gathers into registers before consuming any
    uint4 ub[8];
#pragma unroll
    for (int j = 0; j < 8; ++j)
      ub[j] = *reinterpret_cast<const uint4*>(xq + ((size_t)idx[j] << 6));
#pragma unroll
    for (int j = 0; j < 8; ++j){
      if (base + j < deg){
        uint4 u = ub[j];
        float a0 = __uint_as_float(u.x << 16), a1 = __uint_as_float(u.x & 0xffff0000u);
        float a2 = __uint_as_float(u.y << 16), a3 = __uint_as_float(u.y & 0xffff0000u);
        float a4 = __uint_as_float(u.z << 16), a5 = __uint_as_float(u.z & 0xffff0000u);
        float a6 = __uint_as_float(u.w << 16), a7 = __uint_as_float(u.w & 0xffff0000u);
        s0 += a0; s1 += a1; s2 += a2; s3 += a3;
        s4 += a4; s5 += a5; s6 += a6; s7 += a7;
        m0 = fmaxf(m0, a0); m1 = fmaxf(m1, a1); m2 = fmaxf(m2, a2); m3 = fmaxf(m3, a3);
        m4 = fmaxf(m4, a4); m5 = fmaxf(m5, a5); m6 = fmaxf(m6, a6); m7 = fmaxf(m7, a7);
      }
    }
    pe = pe_n;
  }
  if (r < N){
    const float inv = 1.f / fmaxf((float)deg, 1.f);
    const float gz = (deg > 0) ? 1.f : 0.f;
    const float ca = za0 + za1*inv, cm = za2*gz;
    uint4 o;
    o.x = (u32)f2bf(ca*s0 + cm*m0) | (((u32)f2bf(ca*s1 + cm*m1)) << 16);
    o.y = (u32)f2bf(ca*s2 + cm*m2) | (((u32)f2bf(ca*s3 + cm*m3)) << 16);
    o.z = (u32)f2bf(ca*s4 + cm*m4) | (((u32)f2bf(ca*s5 + cm*m5)) << 16);
    o.w = (u32)f2bf(ca*s6 + cm*m6) | (((u32)f2bf(ca*s7 + cm*m7)) << 16);
    reinterpret_cast<uint4*>(xn + ((size_t)r << 6))[q] = o;
  }
}

extern "C" void kernel_launch(void* const* d_in, const int* in_sizes, int n_in,
                              void* d_out, int out_size, void* d_ws, size_t ws_size,
                              hipStream_t stream){
  const float* x      = (const float*)d_in[0];
  const int*   ei     = (const int*)  d_in[1];
  const float* W_pre  = (const float*)d_in[2];
  const float* b_pre  = (const float*)d_in[3];
  const float* W_self = (const float*)d_in[4];
  const float* b_self = (const float*)d_in[5];
  const float* W_nbr  = (const float*)d_in[6];
  const float* b_nbr  = (const float*)d_in[7];
  const float* W_comb = (const float*)d_in[8];
  const float* b_comb = (const float*)d_in[9];
  const float* W_lc   = (const float*)d_in[10];
  const float* b_lc   = (const float*)d_in[11];
  const float* ln_g   = (const float*)d_in[12];
  const float* ln_b   = (const float*)d_in[13];
  const float* prelu  = (const float*)d_in[14];
  const float* W_lagg = (const float*)d_in[15];
  const float* b_lagg = (const float*)d_in[16];
  const float* W_ff1  = (const float*)d_in[17];
  const float* b_ff1  = (const float*)d_in[18];
  const float* W_ff2  = (const float*)d_in[19];
  const float* b_ff2  = (const float*)d_in[20];
  const float* Z_agg  = (const float*)d_in[21];
  const float* Z_comb = (const float*)d_in[22];
  const float* Z_act  = (const float*)d_in[23];
  const float* Z_lc   = (const float*)d_in[24];
  const float* Z_lagg = (const float*)d_in[25];

  const int N = in_sizes[0] / 128;
  const int E = in_sizes[1] / 2;
  const int* src = ei;
  const int* tgt = ei + E;

  const int nch = DIV_UP(N, CHB);
  const int bstride = (int)(((long)E * CHB) / N) + 2048;

  char* p = (char*)d_ws;
  auto carve = [&](size_t bytes)->void*{
    void* q = (void*)p;
    p += (bytes + 255) & ~(size_t)255;
    return q;
  };
  int* cnt_i = (int*)carve((size_t)N*4);
  int* off   = (int*)carve((size_t)N*4);
  int* bktCnt= (int*)carve(NBKT*4);
  int2* bkt  = (int2*)carve((size_t)NBKT*bstride*8);
  int* perm  = (int*)carve((size_t)NBKT*bstride*4);
  float* WsWct = (float*)carve(3*4096*4);
  float* bsWct = (float*)carve(3*64*4);
  float* W1eff = (float*)carve(3*4096*4);
  float* W2eff = (float*)carve(3*4096*4);
  float* beff  = (float*)carve(3*64*4);
  float* Wlceff= (float*)carve(2*8192*4);
  float* blceff= (float*)carve(2*64*4);
  float* Wle   = (float*)carve(20480*4);
  float* ble   = (float*)carve(64*4);
  u16* pWpre = (u16*)carve(8192*2);
  u16* pWnbr = (u16*)carve(3*4096*2);
  u16* pW1   = (u16*)carve(3*4096*2);
  u16* pW2   = (u16*)carve(3*4096*2);
  u16* pWlc  = (u16*)carve(2*8192*2);
  u16* pWlagg= (u16*)carve(20480*2);
  u16* pWff1 = (u16*)carve(4096*2);
  u16* pWff2 = (u16*)carve(4096*2);
  const size_t AB = (size_t)N*64*2;
  u16* emb0 = (u16*)carve(AB);
  u16* emb1 = (u16*)carve(AB);
  u16* emb2 = (u16*)carve(AB);
  u16* emb3 = (u16*)carve(AB);
  u16* xbuf = (u16*)carve(AB);
  u16* xnl  = (u16*)carve(AB);
  u16* xn   = (u16*)carve(AB);
  u16* mixb = (u16*)carve(AB);

  // ---- CSR build: 256-bucket partition, then per-chunk LDS counting sort ----
  initBkt_k<<<1,NBKT,0,stream>>>(bktCnt, bstride);
  partition_k<<<DIV_UP(E,PTILE),NBKT,0,stream>>>(tgt, src, E, bktCnt, bkt);
  sortChunk_k<<<nch,CHB,0,stream>>>(bkt, bktCnt, bstride, N, cnt_i, off, perm);

  // ---- weight prep ----
  matW_k<<<3*65,64,0,stream>>>(W_self, W_comb, b_self, WsWct, bsWct);
  buildAll_k<<<DIV_UP(49536,256),256,0,stream>>>(W_self, W_comb, b_self, b_comb, Z_comb,
                                                 WsWct, bsWct, W_lc, b_lc, Z_lc,
                                                 W_lagg, b_lagg, Z_lagg,
                                                 W1eff, W2eff, beff, Wlceff, blceff, Wle, ble);

  PackJobs pj;
  pj.src[0] = W_pre;  pj.dst[0] = pWpre;  pj.nkb[0] = 4;
  for (int i = 0; i < 3; ++i){
    pj.src[1+i] = W_nbr + i*4096; pj.dst[1+i] = pWnbr + i*4096; pj.nkb[1+i] = 2;
    pj.src[4+i] = W1eff + i*4096; pj.dst[4+i] = pW1   + i*4096; pj.nkb[4+i] = 2;
    pj.src[7+i] = W2eff + i*4096; pj.dst[7+i] = pW2   + i*4096; pj.nkb[7+i] = 2;
  }
  pj.src[10] = Wlceff;        pj.dst[10] = pWlc;        pj.nkb[10] = 4;
  pj.src[11] = Wlceff + 8192; pj.dst[11] = pWlc + 8192; pj.nkb[11] = 4;
  pj.src[12] = Wle;   pj.dst[12] = pWlagg; pj.nkb[12] = 10;
  pj.src[13] = W_ff1; pj.dst[13] = pWff1;  pj.nkb[13] = 2;
  pj.src[14] = W_ff2; pj.dst[14] = pWff2;  pj.nkb[14] = 2;
  pack_all_k<<<15*16,256,0,stream>>>(pj);

  const int G64 = DIV_UP(N, 64);

  // ---- preprocess (+ fused x_nl layer 0) ----
  gemmP_k<<<G64,256,0,stream>>>(x, pWpre, b_pre, pWnbr, b_nbr, emb0, xnl, N);

  // ---- layers ----
  u16* embs[4] = {emb0, emb1, emb2, emb3};
  const u16* xin = emb0;
  for (int i = 0; i < 3; ++i){
    gather_k<<<DIV_UP(N,32),256,0,stream>>>(xnl, off, cnt_i, perm, Z_agg, i, xn, N);
    if (i < 2){
      gemmCL_k<<<G64,256,0,stream>>>(xin, xn, embs[i],
                                     pW1 + i*4096, pW2 + i*4096,
                                     beff + i*64, ln_g + i*64, ln_b + i*64,
                                     Z_act + i*2, prelu + i,
                                     pWlc + i*8192, blceff + i*64,
                                     pWnbr + (i+1)*4096, b_nbr + (i+1)*64,
                                     embs[i+1], xbuf, xnl, N);
      xin = xbuf;
    } else {
      gemmC_k<<<G64,256,0,stream>>>(xin, xn, pW1 + i*4096, pW2 + i*4096,
                                    beff + i*64, ln_g + i*64, ln_b + i*64,
                                    Z_act + i*2, prelu + i, embs[i+1], N);
    }
  }

  // ---- layer agg (max folded in via zg1*I weight rows) + head ----
  gemmL_k<<<G64,256,0,stream>>>(emb0, emb1, emb2, emb3, pWlagg, ble, mixb, N);
  ff12_k<<<G64,256,0,stream>>>(mixb, pWff1, b_ff1, pWff2, b_ff2, (float*)d_out, N);
}

// Round 10
// 257.734 us; speedup vs baseline: 1.1225x; 1.0416x over previous
//
#include <hip/hip_runtime.h>

typedef unsigned short u16;
typedef unsigned int u32;
using bfrag = __attribute__((ext_vector_type(8))) short;
using f4v   = __attribute__((ext_vector_type(4))) float;

#define DIV_UP(a,b) (((a)+(b)-1)/(b))
#define PTILE 4096
#define CHB 512
#define CHSH 9
#define NBKT 256
#define MFMA(a,b,c) __builtin_amdgcn_mfma_f32_16x16x32_bf16(a,b,c,0,0,0)

__device__ inline u16 f2bf(float f){
  union { float f; u32 u; } v; v.f = f;
  u32 u = v.u;
  return (u16)((u + 0x7fffu + ((u >> 16) & 1u)) >> 16);
}
__device__ inline float bf2f(u16 h){
  union { u32 u; float f; } v; v.u = ((u32)h) << 16;
  return v.f;
}
__device__ inline bfrag ldA(const u16* A, long r, int koff, int lane){
  return *reinterpret_cast<const bfrag*>(A + r*64 + koff + ((lane>>4)<<3));
}
__device__ inline bfrag ldW(const u16* Wf, int kb, int cb, int lane){
  return *reinterpret_cast<const bfrag*>(Wf + (((kb*4+cb)*64 + lane)<<3));
}

// --- per-wave 16x64 C-tile -> A-fragment transpose via swizzled LDS (no barrier) ---
__device__ inline void xpose_store(u16* sT, int lane, const f4v (&acc)[4]){
  const int cl = lane & 15, g = lane >> 4;
#pragma unroll
  for (int j = 0; j < 4; ++j){
    const int lr = g*4 + j;
#pragma unroll
    for (int cb = 0; cb < 4; ++cb){
      const int colblk = cb*2 + (cl >> 3);
      const int gr = colblk ^ (lr & 7);
      sT[lr*64 + gr*8 + (cl & 7)] = f2bf(acc[cb][j]);
    }
  }
}
__device__ inline bfrag xpose_load(const u16* sT, int lane, int kb){
  const int row = lane & 15, colblk = kb*4 + (lane >> 4);
  const int gr = colblk ^ (row & 7);
  return *reinterpret_cast<const bfrag*>(sT + row*64 + gr*8);
}

// ---------------- edge radix-partition into 256 target-chunk buckets ----------------
// bkt entry packs (tgt&511)<<17 | src  (src < 2^17 since N=100000)
__global__ void initBkt_k(int* __restrict__ bktCnt, int bstride){
  if (threadIdx.x < NBKT) bktCnt[threadIdx.x] = threadIdx.x * bstride;
}
__global__ void partition_k(const int* __restrict__ tgt, const int* __restrict__ src,
                            int E, int* __restrict__ bktCnt, u32* __restrict__ bkt){
  __shared__ int sTgt[PTILE], sSrc[PTILE];
  __shared__ int hist[NBKT], base[NBKT], pos[NBKT];
  const int t = threadIdx.x;
  const int e0 = blockIdx.x * PTILE;
  const int n = (e0 + PTILE < E) ? PTILE : (E - e0);
  const int n4 = n >> 2;
  for (int i = t; i < n4; i += NBKT){
    reinterpret_cast<int4*>(sTgt)[i] = reinterpret_cast<const int4*>(tgt + e0)[i];
    reinterpret_cast<int4*>(sSrc)[i] = reinterpret_cast<const int4*>(src + e0)[i];
  }
  for (int i = (n4 << 2) + t; i < n; i += NBKT){
    sTgt[i] = tgt[e0 + i]; sSrc[i] = src[e0 + i];
  }
  hist[t] = 0;
  __syncthreads();
  for (int i = t; i < n; i += NBKT)
    atomicAdd(&hist[sTgt[i] >> CHSH], 1);
  __syncthreads();
  base[t] = (hist[t] > 0) ? atomicAdd(&bktCnt[t], hist[t]) : 0;
  pos[t] = 0;
  __syncthreads();
  for (int i = t; i < n; i += NBKT){
    int tv = sTgt[i], sv = sSrc[i];
    int c = tv >> CHSH;
    int p = base[c] + atomicAdd(&pos[c], 1);
    bkt[p] = ((u32)(tv & (CHB - 1)) << 17) | (u32)sv;
  }
}

// ---------------- per-chunk LDS counting sort: one workgroup per chunk ----------------
__global__ __launch_bounds__(CHB) void sortChunk_k(const u32* __restrict__ bkt,
    const int* __restrict__ bktCnt, int bstride, int N,
    int* __restrict__ cnt, int* __restrict__ off, int* __restrict__ perm){
  __shared__ int hist[CHB], sbase[CHB];
  const int c = blockIdx.x, t = threadIdx.x;
  const int lo = c * CHB;
  const int s = c * bstride, e = bktCnt[c];
  hist[t] = 0;
  __syncthreads();
  for (int i = s + t; i < e; i += CHB)
    atomicAdd(&hist[bkt[i] >> 17], 1);
  __syncthreads();
  const int v = hist[t];
  for (int o = 1; o < CHB; o <<= 1){
    int add = (t >= o) ? hist[t - o] : 0;
    __syncthreads();
    hist[t] += add;
    __syncthreads();
  }
  const int excl = hist[t] - v;
  if (lo + t < N){ cnt[lo + t] = v; off[lo + t] = s + excl; }
  sbase[t] = s + excl;
  __syncthreads();
  hist[t] = 0;
  __syncthreads();
  for (int i = s + t; i < e; i += CHB){
    u32 ed = bkt[i];
    int r = (int)(ed >> 17);
    int p = sbase[r] + atomicAdd(&hist[r], 1);
    perm[p] = (int)(ed & 0x1FFFFu);
  }
}

// ---------------- weight prep: one block per output row (195x64) ----------------
__global__ void matW_k(const float* __restrict__ W_self, const float* __restrict__ W_comb,
                       const float* __restrict__ b_self,
                       float* __restrict__ WsWct, float* __restrict__ bsWct){
  const int b = blockIdx.x;
  const int i = b / 65, r = b % 65;
  const int c = threadIdx.x;
  const float* Wc = W_comb + i*8192;
  float s = 0.f;
  if (r < 64){
    const float* a = W_self + i*4096 + r*64;
#pragma unroll 8
    for (int k = 0; k < 64; ++k) s += a[k] * Wc[k*64 + c];
    WsWct[i*4096 + r*64 + c] = s;
  } else {
    const float* a = b_self + i*64;
#pragma unroll 8
    for (int k = 0; k < 64; ++k) s += a[k] * Wc[k*64 + c];
    bsWct[i*64 + c] = s;
  }
}

// ---------------- all effective-weight builds in one grid-strided kernel ----------------
// Wle is 320x64: rows 0..255 = zg2*W_lagg (+ zg0*I at 192..255), rows 256..319 = zg1*I
__global__ void buildAll_k(const float* __restrict__ W_self, const float* __restrict__ W_comb,
    const float* __restrict__ b_self, const float* __restrict__ b_comb,
    const float* __restrict__ Z_comb, const float* __restrict__ WsWct,
    const float* __restrict__ bsWct,
    const float* __restrict__ W_lc, const float* __restrict__ b_lc,
    const float* __restrict__ Z_lc,
    const float* __restrict__ W_lagg, const float* __restrict__ b_lagg,
    const float* __restrict__ Z_lagg,
    float* __restrict__ W1eff, float* __restrict__ W2eff, float* __restrict__ beff,
    float* __restrict__ Wlceff, float* __restrict__ blceff,
    float* __restrict__ Wle, float* __restrict__ ble){
  int idx = blockIdx.x*blockDim.x + threadIdx.x;
  if (idx < 12288){
    int i = idx >> 12, rem = idx & 4095, k = rem >> 6, c = rem & 63;
    float zc0 = Z_comb[i*2], zc1 = Z_comb[i*2+1];
    W1eff[idx] = zc0*W_self[idx] + zc1*WsWct[idx];
    W2eff[idx] = (k == c ? zc0 : 0.f) + zc1*W_comb[i*8192 + (64 + k)*64 + c];
    return;
  }
  idx -= 12288;
  if (idx < 16384){
    int i = idx >> 13, rem = idx & 8191, k = rem >> 6, c = rem & 63;
    float z0 = Z_lc[i*3], z1 = Z_lc[i*3+1], z2 = Z_lc[i*3+2];
    float idv = (k < 64) ? (k == c ? z1 : 0.f) : ((k - 64) == c ? (z0 + z1) : 0.f);
    Wlceff[idx] = z2*W_lc[idx] + idv;
    return;
  }
  idx -= 16384;
  if (idx < 20480){
    int k = idx >> 6, c = idx & 63;
    float v = (k < 256) ? Z_lagg[2]*W_lagg[idx] : 0.f;
    if (k >= 192 && k < 256 && (k - 192) == c) v += Z_lagg[0];
    if (k >= 256 && (k - 256) == c) v += Z_lagg[1];
    Wle[idx] = v;
    return;
  }
  idx -= 20480;
  if (idx < 192){
    int i = idx >> 6;
    float zc0 = Z_comb[i*2], zc1 = Z_comb[i*2+1];
    beff[idx] = zc0*b_self[idx] + zc1*(bsWct[idx] + b_comb[idx]);
    return;
  }
  idx -= 192;
  if (idx < 128){
    int i = idx >> 6;
    blceff[idx] = Z_lc[i*3+2]*b_lc[idx];
    return;
  }
  idx -= 128;
  if (idx < 64) ble[idx] = Z_lagg[2]*b_lagg[idx];
}

// ---------------- pack fp32 [K][64] -> bf16 MFMA B-fragment layout ----------------
struct PackJobs {
  const float* src[15];
  u16* dst[15];
  int nkb[15];
};
__global__ void pack_all_k(PackJobs pj){
  const int job = blockIdx.x >> 4, kb = blockIdx.x & 15;
  if (kb >= pj.nkb[job]) return;
  const int t = threadIdx.x, cb = t >> 6, lane = t & 63;
  const float* S = pj.src[job];
  u16* D = pj.dst[job] + (((kb*4 + cb)*64 + lane) << 3);
  const int kbase = kb*32 + ((lane >> 4) << 3), c = cb*16 + (lane & 15);
#pragma unroll
  for (int j = 0; j < 8; ++j) D[j] = f2bf(S[(kbase + j)*64 + c]);
}

// ---------------- GEMM pre: fp32 A [N][128] -> emb0, fused xnl0 = emb0@Wnbr0 + bnbr0 ----------------
__global__ __launch_bounds__(256) void gemmP_k(const float* __restrict__ X,
    const u16* __restrict__ Wf, const float* __restrict__ bias,
    const u16* __restrict__ Wn, const float* __restrict__ bn,
    u16* __restrict__ out, u16* __restrict__ xnl, int N){
  __shared__ u16 sT[4][1024];
  const int lane = threadIdx.x & 63, w = threadIdx.x >> 6;
  const int R = blockIdx.x*64 + w*16;
  bfrag wf[4][4], wn[2][4];
#pragma unroll
  for (int kb = 0; kb < 4; ++kb)
#pragma unroll
    for (int cb = 0; cb < 4; ++cb) wf[kb][cb] = ldW(Wf, kb, cb, lane);
#pragma unroll
  for (int kb = 0; kb < 2; ++kb)
#pragma unroll
    for (int cb = 0; cb < 4; ++cb) wn[kb][cb] = ldW(Wn, kb, cb, lane);
  float bv[4], bnv[4];
#pragma unroll
  for (int cb = 0; cb < 4; ++cb){ bv[cb] = bias[cb*16 + (lane & 15)]; bnv[cb] = bn[cb*16 + (lane & 15)]; }
  const long ra = (R + (lane & 15) < N) ? (R + (lane & 15)) : (N - 1);
  f4v acc[4] = {f4v{0,0,0,0}, f4v{0,0,0,0}, f4v{0,0,0,0}, f4v{0,0,0,0}};
#pragma unroll
  for (int kb = 0; kb < 4; ++kb){
    const float* ap = X + ra*128 + kb*32 + ((lane >> 4) << 3);
    float4 q0 = *reinterpret_cast<const float4*>(ap);
    float4 q1 = *reinterpret_cast<const float4*>(ap + 4);
    bfrag a;
    a[0] = (short)f2bf(q0.x); a[1] = (short)f2bf(q0.y);
    a[2] = (short)f2bf(q0.z); a[3] = (short)f2bf(q0.w);
    a[4] = (short)f2bf(q1.x); a[5] = (short)f2bf(q1.y);
    a[6] = (short)f2bf(q1.z); a[7] = (short)f2bf(q1.w);
#pragma unroll
    for (int cb = 0; cb < 4; ++cb) acc[cb] = MFMA(a, wf[kb][cb], acc[cb]);
  }
#pragma unroll
  for (int cb = 0; cb < 4; ++cb)
#pragma unroll
    for (int j = 0; j < 4; ++j) acc[cb][j] += bv[cb];
  const int rbase = R + ((lane >> 4) << 2), cl = lane & 15;
#pragma unroll
  for (int cb = 0; cb < 4; ++cb)
#pragma unroll
    for (int j = 0; j < 4; ++j){
      int r = rbase + j;
      if (r < N) out[(size_t)r*64 + cb*16 + cl] = f2bf(acc[cb][j]);
    }
  // fused x_nl0
  xpose_store(sT[w], lane, acc);
  f4v ac2[4] = {f4v{0,0,0,0}, f4v{0,0,0,0}, f4v{0,0,0,0}, f4v{0,0,0,0}};
#pragma unroll
  for (int kb = 0; kb < 2; ++kb){
    bfrag a = xpose_load(sT[w], lane, kb);
#pragma unroll
    for (int cb = 0; cb < 4; ++cb) ac2[cb] = MFMA(a, wn[kb][cb], ac2[cb]);
  }
#pragma unroll
  for (int cb = 0; cb < 4; ++cb)
#pragma unroll
    for (int j = 0; j < 4; ++j){
      int r = rbase + j;
      if (r < N) xnl[(size_t)r*64 + cb*16 + cl] = f2bf(ac2[cb][j] + bnv[cb]);
    }
}

// ---------------- GEMM combine only (last layer): h -> emb_out ----------------
__global__ __launch_bounds__(256) void gemmC_k(const u16* __restrict__ A1,
    const u16* __restrict__ A2, const u16* __restrict__ Wf1, const u16* __restrict__ Wf2,
    const float* __restrict__ beff, const float* __restrict__ lng, const float* __restrict__ lnb,
    const float* __restrict__ Zact, const float* __restrict__ prelu,
    u16* __restrict__ out, int N){
  const int lane = threadIdx.x & 63, w = threadIdx.x >> 6;
  const int R = blockIdx.x*64 + w*16;
  bfrag wf1[2][4], wf2[2][4];
#pragma unroll
  for (int kb = 0; kb < 2; ++kb)
#pragma unroll
    for (int cb = 0; cb < 4; ++cb){ wf1[kb][cb] = ldW(Wf1, kb, cb, lane); wf2[kb][cb] = ldW(Wf2, kb, cb, lane); }
  float bv[4], lgv[4], lbv[4];
#pragma unroll
  for (int cb = 0; cb < 4; ++cb){
    int c = cb*16 + (lane & 15);
    bv[cb] = beff[c]; lgv[cb] = lng[c]; lbv[cb] = lnb[c];
  }
  const float zt0 = Zact[0], zt1 = Zact[1], pw = prelu[0];
  const long ra = (R + (lane & 15) < N) ? (R + (lane & 15)) : (N - 1);
  f4v acc[4] = {f4v{0,0,0,0}, f4v{0,0,0,0}, f4v{0,0,0,0}, f4v{0,0,0,0}};
#pragma unroll
  for (int kb = 0; kb < 2; ++kb){
    bfrag a = ldA(A1, ra, kb*32, lane);
#pragma unroll
    for (int cb = 0; cb < 4; ++cb) acc[cb] = MFMA(a, wf1[kb][cb], acc[cb]);
  }
#pragma unroll
  for (int kb = 0; kb < 2; ++kb){
    bfrag a = ldA(A2, ra, kb*32, lane);
#pragma unroll
    for (int cb = 0; cb < 4; ++cb) acc[cb] = MFMA(a, wf2[kb][cb], acc[cb]);
  }
#pragma unroll
  for (int cb = 0; cb < 4; ++cb)
#pragma unroll
    for (int j = 0; j < 4; ++j){
      float v = acc[cb][j] + bv[cb];
      v = zt0*fmaxf(v, 0.f) + zt1*((v > 0.f) ? v : pw*v);
      acc[cb][j] = v;
    }
  const int rbase = R + ((lane >> 4) << 2), cl = lane & 15;
#pragma unroll
  for (int j = 0; j < 4; ++j){
    float s = acc[0][j] + acc[1][j] + acc[2][j] + acc[3][j];
    s += __shfl_xor(s, 1, 64); s += __shfl_xor(s, 2, 64);
    s += __shfl_xor(s, 4, 64); s += __shfl_xor(s, 8, 64);
    float mu = s * 0.015625f;
    float d0 = acc[0][j]-mu, d1 = acc[1][j]-mu, d2 = acc[2][j]-mu, d3 = acc[3][j]-mu;
    float q = d0*d0 + d1*d1 + d2*d2 + d3*d3;
    q += __shfl_xor(q, 1, 64); q += __shfl_xor(q, 2, 64);
    q += __shfl_xor(q, 4, 64); q += __shfl_xor(q, 8, 64);
    float sd = rsqrtf(q * 0.015625f + 1e-5f);
    int r = rbase + j;
    if (r < N){
      out[(size_t)r*64 +  0 + cl] = f2bf(d0*sd*lgv[0] + lbv[0]);
      out[(size_t)r*64 + 16 + cl] = f2bf(d1*sd*lgv[1] + lbv[1]);
      out[(size_t)r*64 + 32 + cl] = f2bf(d2*sd*lgv[2] + lbv[2]);
      out[(size_t)r*64 + 48 + cl] = f2bf(d3*sd*lgv[3] + lbv[3]);
    }
  }
}

// ---------------- fused layer: combine+act+LN -> emb_out, then lc -> x_out, then x_nl ----------------
__global__ __launch_bounds__(256) void gemmCL_k(const u16* __restrict__ A1,
    const u16* __restrict__ A2, const u16* __restrict__ Aprev,
    const u16* __restrict__ Wf1, const u16* __restrict__ Wf2,
    const float* __restrict__ beff, const float* __restrict__ lng, const float* __restrict__ lnb,
    const float* __restrict__ Zact, const float* __restrict__ prelu,
    const u16* __restrict__ Wlc, const float* __restrict__ blc,
    const u16* __restrict__ Wn, const float* __restrict__ bn,
    u16* __restrict__ emb_out, u16* __restrict__ x_out, u16* __restrict__ xnl, int N){
  __shared__ u16 sT[4][1024];
  const int lane = threadIdx.x & 63, w = threadIdx.x >> 6;
  const int R = blockIdx.x*64 + w*16;
  bfrag wf1[2][4], wf2[2][4];
#pragma unroll
  for (int kb = 0; kb < 2; ++kb)
#pragma unroll
    for (int cb = 0; cb < 4; ++cb){ wf1[kb][cb] = ldW(Wf1, kb, cb, lane); wf2[kb][cb] = ldW(Wf2, kb, cb, lane); }
  float bv[4], lgv[4], lbv[4], blcv[4], bnv[4];
#pragma unroll
  for (int cb = 0; cb < 4; ++cb){
    int c = cb*16 + (lane & 15);
    bv[cb] = beff[c]; lgv[cb] = lng[c]; lbv[cb] = lnb[c];
    blcv[cb] = blc[c]; bnv[cb] = bn[c];
  }
  const float zt0 = Zact[0], zt1 = Zact[1], pw = prelu[0];
  const long ra = (R + (lane & 15) < N) ? (R + (lane & 15)) : (N - 1);
  f4v acc[4] = {f4v{0,0,0,0}, f4v{0,0,0,0}, f4v{0,0,0,0}, f4v{0,0,0,0}};
#pragma unroll
  for (int kb = 0; kb < 2; ++kb){
    bfrag a = ldA(A1, ra, kb*32, lane);
#pragma unroll
    for (int cb = 0; cb < 4; ++cb) acc[cb] = MFMA(a, wf1[kb][cb], acc[cb]);
  }
#pragma unroll
  for (int kb = 0; kb < 2; ++kb){
    bfrag a = ldA(A2, ra, kb*32, lane);
#pragma unroll
    for (int cb = 0; cb < 4; ++cb) acc[cb] = MFMA(a, wf2[kb][cb], acc[cb]);
  }
#pragma unroll
  for (int cb = 0; cb < 4; ++cb)
#pragma unroll
    for (int j = 0; j < 4; ++j){
      float v = acc[cb][j] + bv[cb];
      v = zt0*fmaxf(v, 0.f) + zt1*((v > 0.f) ? v : pw*v);
      acc[cb][j] = v;
    }
  const int rbase = R + ((lane >> 4) << 2), cl = lane & 15;
#pragma unroll
  for (int j = 0; j < 4; ++j){
    float s = acc[0][j] + acc[1][j] + acc[2][j] + acc[3][j];
    s += __shfl_xor(s, 1, 64); s += __shfl_xor(s, 2, 64);
    s += __shfl_xor(s, 4, 64); s += __shfl_xor(s, 8, 64);
    float mu = s * 0.015625f;
    float d0 = acc[0][j]-mu, d1 = acc[1][j]-mu, d2 = acc[2][j]-mu, d3 = acc[3][j]-mu;
    float q = d0*d0 + d1*d1 + d2*d2 + d3*d3;
    q += __shfl_xor(q, 1, 64); q += __shfl_xor(q, 2, 64);
    q += __shfl_xor(q, 4, 64); q += __shfl_xor(q, 8, 64);
    float sd = rsqrtf(q * 0.015625f + 1e-5f);
    acc[0][j] = d0*sd*lgv[0] + lbv[0];
    acc[1][j] = d1*sd*lgv[1] + lbv[1];
    acc[2][j] = d2*sd*lgv[2] + lbv[2];
    acc[3][j] = d3*sd*lgv[3] + lbv[3];
    int r = rbase + j;
    if (r < N){
      emb_out[(size_t)r*64 +  0 + cl] = f2bf(acc[0][j]);
      emb_out[(size_t)r*64 + 16 + cl] = f2bf(acc[1][j]);
      emb_out[(size_t)r*64 + 32 + cl] = f2bf(acc[2][j]);
      emb_out[(size_t)r*64 + 48 + cl] = f2bf(acc[3][j]);
    }
  }
  // ---- stage 2: layer-connect, h consumed via xpose (K=128: [Aprev, h]) ----
  xpose_store(sT[w], lane, acc);
  f4v ac2[4] = {f4v{0,0,0,0}, f4v{0,0,0,0}, f4v{0,0,0,0}, f4v{0,0,0,0}};
#pragma unroll
  for (int kb = 0; kb < 4; ++kb){
    bfrag a = (kb < 2) ? ldA(Aprev, ra, kb*32, lane) : xpose_load(sT[w], lane, kb - 2);
#pragma unroll
    for (int cb = 0; cb < 4; ++cb) ac2[cb] = MFMA(a, ldW(Wlc, kb, cb, lane), ac2[cb]);
  }
#pragma unroll
  for (int cb = 0; cb < 4; ++cb)
#pragma unroll
    for (int j = 0; j < 4; ++j) ac2[cb][j] += blcv[cb];
#pragma unroll
  for (int cb = 0; cb < 4; ++cb)
#pragma unroll
    for (int j = 0; j < 4; ++j){
      int r = rbase + j;
      if (r < N) x_out[(size_t)r*64 + cb*16 + cl] = f2bf(ac2[cb][j]);
    }
  // ---- stage 3: next layer's x_nl = x_out @ Wn + bn ----
  xpose_store(sT[w], lane, ac2);
  f4v ac3[4] = {f4v{0,0,0,0}, f4v{0,0,0,0}, f4v{0,0,0,0}, f4v{0,0,0,0}};
#pragma unroll
  for (int kb = 0; kb < 2; ++kb){
    bfrag a = xpose_load(sT[w], lane, kb);
#pragma unroll
    for (int cb = 0; cb < 4; ++cb) ac3[cb] = MFMA(a, ldW(Wn, kb, cb, lane), ac3[cb]);
  }
#pragma unroll
  for (int cb = 0; cb < 4; ++cb)
#pragma unroll
    for (int j = 0; j < 4; ++j){
      int r = rbase + j;
      if (r < N) xnl[(size_t)r*64 + cb*16 + cl] = f2bf(ac3[cb][j] + bnv[cb]);
    }
}

// ---------------- fused layer-agg (K=320 incl. max) + FF head -> fp32 out ----------------
__global__ __launch_bounds__(256) void gemmLF_k(const u16* __restrict__ e0,
    const u16* __restrict__ e1, const u16* __restrict__ e2, const u16* __restrict__ e3,
    const u16* __restrict__ Wf, const float* __restrict__ bias,
    const u16* __restrict__ Wf1, const float* __restrict__ b1,
    const u16* __restrict__ Wf2, const float* __restrict__ b2,
    float* __restrict__ out, int N){
  __shared__ u16 sT[4][1024];
  const int lane = threadIdx.x & 63, w = threadIdx.x >> 6;
  const int R = blockIdx.x*64 + w*16;
  const u16* Ab[4] = {e0, e1, e2, e3};
  float bv[4], bv1[4], bv2[4];
#pragma unroll
  for (int cb = 0; cb < 4; ++cb){
    int c = cb*16 + (lane & 15);
    bv[cb] = bias[c]; bv1[cb] = b1[c]; bv2[cb] = b2[c];
  }
  const long ra = (R + (lane & 15) < N) ? (R + (lane & 15)) : (N - 1);
  f4v acc[4] = {f4v{0,0,0,0}, f4v{0,0,0,0}, f4v{0,0,0,0}, f4v{0,0,0,0}};
  bfrag mx[2];
#pragma unroll
  for (int kb = 0; kb < 8; ++kb){
    bfrag a = ldA(Ab[kb >> 1], ra, (kb & 1)*32, lane);
    if (kb < 2){ mx[kb] = a; }
    else {
      bfrag& m = mx[kb & 1];
#pragma unroll
      for (int i = 0; i < 8; ++i)
        m[i] = (short)f2bf(fmaxf(bf2f((u16)m[i]), bf2f((u16)a[i])));
    }
#pragma unroll
    for (int cb = 0; cb < 4; ++cb) acc[cb] = MFMA(a, ldW(Wf, kb, cb, lane), acc[cb]);
  }
#pragma unroll
  for (int kb = 8; kb < 10; ++kb)
#pragma unroll
    for (int cb = 0; cb < 4; ++cb) acc[cb] = MFMA(mx[kb-8], ldW(Wf, kb, cb, lane), acc[cb]);
#pragma unroll
  for (int cb = 0; cb < 4; ++cb)
#pragma unroll
    for (int j = 0; j < 4; ++j) acc[cb][j] += bv[cb];
  // ---- ff1: relu(mix@W1+b1) ----
  xpose_store(sT[w], lane, acc);
  f4v ac2[4] = {f4v{0,0,0,0}, f4v{0,0,0,0}, f4v{0,0,0,0}, f4v{0,0,0,0}};
#pragma unroll
  for (int kb = 0; kb < 2; ++kb){
    bfrag a = xpose_load(sT[w], lane, kb);
#pragma unroll
    for (int cb = 0; cb < 4; ++cb) ac2[cb] = MFMA(a, ldW(Wf1, kb, cb, lane), ac2[cb]);
  }
#pragma unroll
  for (int cb = 0; cb < 4; ++cb)
#pragma unroll
    for (int j = 0; j < 4; ++j) ac2[cb][j] = fmaxf(ac2[cb][j] + bv1[cb], 0.f);
  // ---- ff2 -> fp32 out ----
  xpose_store(sT[w], lane, ac2);
  f4v ac3[4] = {f4v{0,0,0,0}, f4v{0,0,0,0}, f4v{0,0,0,0}, f4v{0,0,0,0}};
#pragma unroll
  for (int kb = 0; kb < 2; ++kb){
    bfrag a = xpose_load(sT[w], lane, kb);
#pragma unroll
    for (int cb = 0; cb < 4; ++cb) ac3[cb] = MFMA(a, ldW(Wf2, kb, cb, lane), ac3[cb]);
  }
  const int rbase = R + ((lane >> 4) << 2), cl = lane & 15;
#pragma unroll
  for (int cb = 0; cb < 4; ++cb)
#pragma unroll
    for (int j = 0; j < 4; ++j){
      int r = rbase + j;
      if (r < N) out[(size_t)r*64 + cb*16 + cl] = ac3[cb][j] + bv2[cb];
    }
}

// ---------------- neighbor aggregate: 8 rows/wave, ping-pong 16-deep load pipeline ----------------
__global__ __launch_bounds__(256) void gather_k(const u16* __restrict__ xnl,
    const int* __restrict__ off, const int* __restrict__ cnt, const int* __restrict__ perm,
    const float* __restrict__ Z_agg, int layer, u16* __restrict__ xn, int N){
  const int lane = threadIdx.x & 63, w = threadIdx.x >> 6;
  const int g = lane >> 3;            // row slot (0..7)
  const int q = lane & 7;             // channel octet
  const int gbase = lane & 56;
  const int r = blockIdx.x*32 + w*8 + g;
  const float za0 = Z_agg[layer*3+0], za1 = Z_agg[layer*3+1], za2 = Z_agg[layer*3+2];
  int e0 = 0, deg = 0;
  if (r < N){ e0 = off[r]; deg = cnt[r]; }
  const float NI = -3.402823466e38f;
  float s[8], m[8];
#pragma unroll
  for (int k = 0; k < 8; ++k){ s[k] = 0.f; m[k] = NI; }
  const u16* xq = xnl + q*8;          // lane's channel-octet base
  auto consume = [&](const uint4 (&ub)[8], int base){
#pragma unroll
    for (int j = 0; j < 8; ++j){
      if (base + j < deg){
        const uint4 u = ub[j];
        float a0 = __uint_as_float(u.x << 16), a1 = __uint_as_float(u.x & 0xffff0000u);
        float a2 = __uint_as_float(u.y << 16), a3 = __uint_as_float(u.y & 0xffff0000u);
        float a4 = __uint_as_float(u.z << 16), a5 = __uint_as_float(u.z & 0xffff0000u);
        float a6 = __uint_as_float(u.w << 16), a7 = __uint_as_float(u.w & 0xffff0000u);
        s[0] += a0; s[1] += a1; s[2] += a2; s[3] += a3;
        s[4] += a4; s[5] += a5; s[6] += a6; s[7] += a7;
        m[0] = fmaxf(m[0], a0); m[1] = fmaxf(m[1], a1);
        m[2] = fmaxf(m[2], a2); m[3] = fmaxf(m[3], a3);
        m[4] = fmaxf(m[4], a4); m[5] = fmaxf(m[5], a5);
        m[6] = fmaxf(m[6], a6); m[7] = fmaxf(m[7], a7);
      }
    }
  };
  int idxA[8]; uint4 ubA[8];
  int idxB[8]; uint4 ubB[8];
  {
    int pe = (q < deg) ? perm[e0 + q] : 0;
#pragma unroll
    for (int j = 0; j < 8; ++j) idxA[j] = __shfl(pe, gbase + j, 64);
#pragma unroll
    for (int j = 0; j < 8; ++j)
      ubA[j] = *reinterpret_cast<const uint4*>(xq + ((size_t)idxA[j] << 6));
  }
  for (int base = 0; base < deg; base += 16){
    // issue B = batch at base+8 while A is in flight / being consumed
    {
      int pe = (base + 8 + q < deg) ? perm[e0 + base + 8 + q] : 0;
#pragma unroll
      for (int j = 0; j < 8; ++j) idxB[j] = __shfl(pe, gbase + j, 64);
#pragma unroll
      for (int j = 0; j < 8; ++j)
        ubB[j] = *reinterpret_cast<const uint4*>(xq + ((size_t)idxB[j] << 6));
    }
    consume(ubA, base);
    // issue A = batch at base+16
    {
      int pe = (base + 16 + q < deg) ? perm[e0 + base + 16 + q] : 0;
#pragma unroll
      for (int j = 0; j < 8; ++j) idxA[j] = __shfl(pe, gbase + j, 64);
#pragma unroll
      for (int j = 0; j < 8; ++j)
        ubA[j] = *reinterpret_cast<const uint4*>(xq + ((size_t)idxA[j] << 6));
    }
    consume(ubB, base + 8);
  }
  if (r < N){
    const float inv = 1.f / fmaxf((float)deg, 1.f);
    const float gz = (deg > 0) ? 1.f : 0.f;
    const float ca = za0 + za1*inv, cm = za2*gz;
    uint4 o;
    o.x = (u32)f2bf(ca*s[0] + cm*m[0]) | (((u32)f2bf(ca*s[1] + cm*m[1])) << 16);
    o.y = (u32)f2bf(ca*s[2] + cm*m[2]) | (((u32)f2bf(ca*s[3] + cm*m[3])) << 16);
    o.z = (u32)f2bf(ca*s[4] + cm*m[4]) | (((u32)f2bf(ca*s[5] + cm*m[5])) << 16);
    o.w = (u32)f2bf(ca*s[6] + cm*m[6]) | (((u32)f2bf(ca*s[7] + cm*m[7])) << 16);
    reinterpret_cast<uint4*>(xn + ((size_t)r << 6))[q] = o;
  }
}

extern "C" void kernel_launch(void* const* d_in, const int* in_sizes, int n_in,
                              void* d_out, int out_size, void* d_ws, size_t ws_size,
                              hipStream_t stream){
  const float* x      = (const float*)d_in[0];
  const int*   ei     = (const int*)  d_in[1];
  const float* W_pre  = (const float*)d_in[2];
  const float* b_pre  = (const float*)d_in[3];
  const float* W_self = (const float*)d_in[4];
  const float* b_self = (const float*)d_in[5];
  const float* W_nbr  = (const float*)d_in[6];
  const float* b_nbr  = (const float*)d_in[7];
  const float* W_comb = (const float*)d_in[8];
  const float* b_comb = (const float*)d_in[9];
  const float* W_lc   = (const float*)d_in[10];
  const float* b_lc   = (const float*)d_in[11];
  const float* ln_g   = (const float*)d_in[12];
  const float* ln_b   = (const float*)d_in[13];
  const float* prelu  = (const float*)d_in[14];
  const float* W_lagg = (const float*)d_in[15];
  const float* b_lagg = (const float*)d_in[16];
  const float* W_ff1  = (const float*)d_in[17];
  const float* b_ff1  = (const float*)d_in[18];
  const float* W_ff2  = (const float*)d_in[19];
  const float* b_ff2  = (const float*)d_in[20];
  const float* Z_agg  = (const float*)d_in[21];
  const float* Z_comb = (const float*)d_in[22];
  const float* Z_act  = (const float*)d_in[23];
  const float* Z_lc   = (const float*)d_in[24];
  const float* Z_lagg = (const float*)d_in[25];

  const int N = in_sizes[0] / 128;
  const int E = in_sizes[1] / 2;
  const int* src = ei;
  const int* tgt = ei + E;

  const int nch = DIV_UP(N, CHB);
  const int bstride = (int)(((long)E * CHB) / N) + 2048;

  char* p = (char*)d_ws;
  auto carve = [&](size_t bytes)->void*{
    void* q = (void*)p;
    p += (bytes + 255) & ~(size_t)255;
    return q;
  };
  int* cnt_i = (int*)carve((size_t)N*4);
  int* off   = (int*)carve((size_t)N*4);
  int* bktCnt= (int*)carve(NBKT*4);
  u32* bkt   = (u32*)carve((size_t)NBKT*bstride*4);
  int* perm  = (int*)carve((size_t)NBKT*bstride*4);
  float* WsWct = (float*)carve(3*4096*4);
  float* bsWct = (float*)carve(3*64*4);
  float* W1eff = (float*)carve(3*4096*4);
  float* W2eff = (float*)carve(3*4096*4);
  float* beff  = (float*)carve(3*64*4);
  float* Wlceff= (float*)carve(2*8192*4);
  float* blceff= (float*)carve(2*64*4);
  float* Wle   = (float*)carve(20480*4);
  float* ble   = (float*)carve(64*4);
  u16* pWpre = (u16*)carve(8192*2);
  u16* pWnbr = (u16*)carve(3*4096*2);
  u16* pW1   = (u16*)carve(3*4096*2);
  u16* pW2   = (u16*)carve(3*4096*2);
  u16* pWlc  = (u16*)carve(2*8192*2);
  u16* pWlagg= (u16*)carve(20480*2);
  u16* pWff1 = (u16*)carve(4096*2);
  u16* pWff2 = (u16*)carve(4096*2);
  const size_t AB = (size_t)N*64*2;
  u16* emb0 = (u16*)carve(AB);
  u16* emb1 = (u16*)carve(AB);
  u16* emb2 = (u16*)carve(AB);
  u16* emb3 = (u16*)carve(AB);
  u16* xbuf = (u16*)carve(AB);
  u16* xnl  = (u16*)carve(AB);
  u16* xn   = (u16*)carve(AB);

  // ---- CSR build: 256-bucket partition (packed u32), then per-chunk LDS counting sort ----
  initBkt_k<<<1,NBKT,0,stream>>>(bktCnt, bstride);
  partition_k<<<DIV_UP(E,PTILE),NBKT,0,stream>>>(tgt, src, E, bktCnt, bkt);
  sortChunk_k<<<nch,CHB,0,stream>>>(bkt, bktCnt, bstride, N, cnt_i, off, perm);

  // ---- weight prep ----
  matW_k<<<3*65,64,0,stream>>>(W_self, W_comb, b_self, WsWct, bsWct);
  buildAll_k<<<DIV_UP(49536,256),256,0,stream>>>(W_self, W_comb, b_self, b_comb, Z_comb,
                                                 WsWct, bsWct, W_lc, b_lc, Z_lc,
                                                 W_lagg, b_lagg, Z_lagg,
                                                 W1eff, W2eff, beff, Wlceff, blceff, Wle, ble);

  PackJobs pj;
  pj.src[0] = W_pre;  pj.dst[0] = pWpre;  pj.nkb[0] = 4;
  for (int i = 0; i < 3; ++i){
    pj.src[1+i] = W_nbr + i*4096; pj.dst[1+i] = pWnbr + i*4096; pj.nkb[1+i] = 2;
    pj.src[4+i] = W1eff + i*4096; pj.dst[4+i] = pW1   + i*4096; pj.nkb[4+i] = 2;
    pj.src[7+i] = W2eff + i*4096; pj.dst[7+i] = pW2   + i*4096; pj.nkb[7+i] = 2;
  }
  pj.src[10] = Wlceff;        pj.dst[10] = pWlc;        pj.nkb[10] = 4;
  pj.src[11] = Wlceff + 8192; pj.dst[11] = pWlc + 8192; pj.nkb[11] = 4;
  pj.src[12] = Wle;   pj.dst[12] = pWlagg; pj.nkb[12] = 10;
  pj.src[13] = W_ff1; pj.dst[13] = pWff1;  pj.nkb[13] = 2;
  pj.src[14] = W_ff2; pj.dst[14] = pWff2;  pj.nkb[14] = 2;
  pack_all_k<<<15*16,256,0,stream>>>(pj);

  const int G64 = DIV_UP(N, 64);

  // ---- preprocess (+ fused x_nl layer 0) ----
  gemmP_k<<<G64,256,0,stream>>>(x, pWpre, b_pre, pWnbr, b_nbr, emb0, xnl, N);

  // ---- layers ----
  u16* embs[4] = {emb0, emb1, emb2, emb3};
  const u16* xin = emb0;
  for (int i = 0; i < 3; ++i){
    gather_k<<<DIV_UP(N,32),256,0,stream>>>(xnl, off, cnt_i, perm, Z_agg, i, xn, N);
    if (i < 2){
      gemmCL_k<<<G64,256,0,stream>>>(xin, xn, embs[i],
                                     pW1 + i*4096, pW2 + i*4096,
                                     beff + i*64, ln_g + i*64, ln_b + i*64,
                                     Z_act + i*2, prelu + i,
                                     pWlc + i*8192, blceff + i*64,
                                     pWnbr + (i+1)*4096, b_nbr + (i+1)*64,
                                     embs[i+1], xbuf, xnl, N);
      xin = xbuf;
    } else {
      gemmC_k<<<G64,256,0,stream>>>(xin, xn, pW1 + i*4096, pW2 + i*4096,
                                    beff + i*64, ln_g + i*64, ln_b + i*64,
                                    Z_act + i*2, prelu + i, embs[i+1], N);
    }
  }

  // ---- fused layer-agg (max folded via zg1*I rows) + FF head ----
  gemmLF_k<<<G64,256,0,stream>>>(emb0, emb1, emb2, emb3, pWlagg, ble,
                                 pWff1, b_ff1, pWff2, b_ff2, (float*)d_out, N);
}